// Round 1
// baseline (132.220 us; speedup 1.0000x reference)
//
#include <hip/hip_runtime.h>
#include <hip/hip_bf16.h>
#include <math.h>

// Problem dims (fixed by reference setup_inputs): B=1, H=16, L=2048, D=64
// Chunked linear-recurrence decomposition, chunk C=64, NC=32.

#define H 16
#define L 2048
#define D 64
#define C 64
#define NC 32
#define PITCH 65

__device__ inline float wave_sum(float x) {
  #pragma unroll
  for (int off = 32; off > 0; off >>= 1) x += __shfl_xor(x, off, 64);
  return x;
}

// ---------------- Kernel 1: grad_l (fused LN-L2 backward), store gt = -eta*grad_l
__global__ __launch_bounds__(256) void k_gradl(
    const float* __restrict__ K, const float* __restrict__ V,
    const float* __restrict__ eta, const float* __restrict__ W0,
    const float* __restrict__ gamma, const float* __restrict__ beta,
    float* __restrict__ gt)
{
  int tid = threadIdx.x;
  int lane = tid & 63;
  int row = blockIdx.x * 4 + (tid >> 6);   // [0, H*L)
  int h = row >> 11;                       // L = 2048
  const float* w0 = W0 + h * (D * D) + lane;
  float ke = K[row * D + lane];
  float z1 = 0.f;
  #pragma unroll
  for (int d = 0; d < D; ++d) {
    float kd = __shfl(ke, d, 64);
    z1 = fmaf(kd, w0[d * D], z1);
  }
  float mu  = wave_sum(z1) * (1.f / 64.f);
  float t   = z1 - mu;
  float var = wave_sum(t * t) * (1.f / 64.f);
  float rstd = rsqrtf(var + 1e-6f);
  float xh = t * rstd;
  float ga = gamma[h * D + lane], be = beta[h * D + lane];
  float go = 2.f * (fmaf(ga, xh, be) + ke - V[row * D + lane]);
  float gxh = go * ga;
  float m1 = wave_sum(gxh) * (1.f / 64.f);
  float m2 = wave_sum(gxh * xh) * (1.f / 64.f);
  float z = (gxh - m1 - xh * m2) * rstd;
  gt[row * D + lane] = -eta[row] * z;
}

// ---------------- Kernel 2: per-chunk local work.
// Computes: P[i]=exp(cl[i]) (cum-gate within chunk), intra-chunk Zq part (-> outIntra),
// chunk update matrix U[d][e] = sum_j exp(cl63-cl_j) k[j][d] gt[j][e].
__global__ __launch_bounds__(256) void k_chunk(
    const float* __restrict__ Q, const float* __restrict__ K,
    const float* __restrict__ gate, const float* __restrict__ gtg,
    float* __restrict__ U, float* __restrict__ P, float* __restrict__ outIntra)
{
  __shared__ float qs[64 * PITCH];   // reused as S after A-matmul
  __shared__ float ks[64 * PITCH];
  __shared__ float gs[64 * PITCH];
  __shared__ double cl[64];
  __shared__ float wj[64];
  int tid = threadIdx.x;
  int h = blockIdx.x >> 5;   // NC = 32
  int c = blockIdx.x & 31;
  int rowb = h * L + c * C;

  // stage q, k, gt for this chunk
  for (int idx = tid; idx < 64 * 64; idx += 256) {
    int j = idx >> 6, d = idx & 63;
    qs[j * PITCH + d] = Q[(rowb + j) * D + d];
    ks[j * PITCH + d] = K[(rowb + j) * D + d];
    gs[j * PITCH + d] = gtg[(rowb + j) * D + d];
  }
  if (tid < 64) {
    double x = log((double)fmaxf(gate[rowb + tid], 1e-30f));
    #pragma unroll
    for (int off = 1; off < 64; off <<= 1) {
      double n = __shfl_up(x, off, 64);
      if (tid >= off) x += n;
    }
    cl[tid] = x;
    double c63 = __shfl(x, 63, 64);
    wj[tid] = expf((float)(c63 - x));
    P[h * L + c * C + tid] = expf((float)x);
  }
  __syncthreads();

  // A[i][j] = q_i . k_j ; thread: i = tid>>2, j-block jg = tid&3 (16 j's each)
  int i  = tid >> 2;
  int jg = tid & 3;
  float acc[16];
  #pragma unroll
  for (int jj = 0; jj < 16; ++jj) acc[jj] = 0.f;
  for (int d = 0; d < 64; ++d) {
    float qv = qs[i * PITCH + d];
    #pragma unroll
    for (int jj = 0; jj < 16; ++jj)
      acc[jj] = fmaf(qv, ks[(jg * 16 + jj) * PITCH + d], acc[jj]);
  }
  double cli = cl[i];
  __syncthreads();           // everyone done reading qs

  // S[i][j] = (j<=i) ? A[i][j]*exp(cl_i - cl_j) : 0 ; store into qs region
  #pragma unroll
  for (int jj = 0; jj < 16; ++jj) {
    int j = jg * 16 + jj;
    float s = (j <= i) ? acc[jj] * expf((float)(cli - cl[j])) : 0.f;
    qs[i * PITCH + j] = s;
  }
  __syncthreads();

  // Intra[i][e] = sum_j S[i][j] * gt[j][e] ; thread: i = tid>>2, e-block eg = tid&3
  int eg = jg;
  float facc[16];
  #pragma unroll
  for (int ee = 0; ee < 16; ++ee) facc[ee] = 0.f;
  for (int j = 0; j < 64; ++j) {
    float sv = qs[i * PITCH + j];
    #pragma unroll
    for (int ee = 0; ee < 16; ++ee)
      facc[ee] = fmaf(sv, gs[j * PITCH + eg * 16 + ee], facc[ee]);
  }
  #pragma unroll
  for (int ee = 0; ee < 16; ++ee)
    outIntra[(rowb + i) * D + eg * 16 + ee] = facc[ee];

  // U[d][e] = sum_j (wj[j]*k[j][d]) * gt[j][e] ; thread: d = tid>>2, eg
  int d = i;
  #pragma unroll
  for (int ee = 0; ee < 16; ++ee) facc[ee] = 0.f;
  for (int j = 0; j < 64; ++j) {
    float kv = ks[j * PITCH + d] * wj[j];
    #pragma unroll
    for (int ee = 0; ee < 16; ++ee)
      facc[ee] = fmaf(kv, gs[j * PITCH + eg * 16 + ee], facc[ee]);
  }
  float* Ub = U + (h * NC + c) * (D * D);
  #pragma unroll
  for (int ee = 0; ee < 16; ++ee)
    Ub[d * D + eg * 16 + ee] = facc[ee];
}

// ---------------- Kernel 3: sequential chunk-state scan (per head).
// Stores W_prev (state BEFORE chunk c) for each chunk; W = Gc*W + U_c.
__global__ __launch_bounds__(256) void k_scan(
    const float* __restrict__ W0, const float* __restrict__ U,
    const float* __restrict__ P, float* __restrict__ Wprev)
{
  int tid = threadIdx.x;
  int h = blockIdx.x;
  float w[16];
  #pragma unroll
  for (int j = 0; j < 16; ++j) w[j] = W0[h * (D * D) + j * 256 + tid];
  for (int c = 0; c < NC; ++c) {
    float* wp = Wprev + (h * NC + c) * (D * D);
    #pragma unroll
    for (int j = 0; j < 16; ++j) wp[j * 256 + tid] = w[j];
    float gc = P[h * L + c * C + 63];
    const float* Ub = U + (h * NC + c) * (D * D);
    #pragma unroll
    for (int j = 0; j < 16; ++j) w[j] = fmaf(gc, w[j], Ub[j * 256 + tid]);
  }
}

// ---------------- Kernel 4: Zq = P*(q @ W_prev) + intra ; LN fwd ; +q
__global__ __launch_bounds__(256) void k_out(
    const float* __restrict__ Q, const float* __restrict__ Wprev,
    const float* __restrict__ P, const float* __restrict__ gamma,
    const float* __restrict__ beta, float* __restrict__ Out)
{
  __shared__ float Wl[D * D];
  int tid = threadIdx.x;
  int lane = tid & 63;
  int wv = tid >> 6;
  int h = blockIdx.x >> 5;
  int c = blockIdx.x & 31;
  int rowb = h * L + c * C;
  const float* wp = Wprev + (h * NC + c) * (D * D);
  for (int idx = tid; idx < D * D; idx += 256) Wl[idx] = wp[idx];
  __syncthreads();
  float ga = gamma[h * D + lane], be = beta[h * D + lane];
  for (int i0 = 0; i0 < 16; ++i0) {
    int i = wv * 16 + i0;
    int row = rowb + i;
    float qe = Q[row * D + lane];
    float acc = 0.f;
    #pragma unroll
    for (int d = 0; d < D; ++d) {
      float qd = __shfl(qe, d, 64);
      acc = fmaf(qd, Wl[d * D + lane], acc);
    }
    float zq = fmaf(P[row], acc, Out[row * D + lane]);
    float mu  = wave_sum(zq) * (1.f / 64.f);
    float t   = zq - mu;
    float var = wave_sum(t * t) * (1.f / 64.f);
    float xh = t * rsqrtf(var + 1e-6f);
    Out[row * D + lane] = fmaf(ga, xh, be) + qe;
  }
}

extern "C" void kernel_launch(void* const* d_in, const int* in_sizes, int n_in,
                              void* d_out, int out_size, void* d_ws, size_t ws_size,
                              hipStream_t stream) {
  const float* q     = (const float*)d_in[0];
  const float* k     = (const float*)d_in[1];
  const float* v     = (const float*)d_in[2];
  const float* gate  = (const float*)d_in[3];
  const float* eta   = (const float*)d_in[4];
  const float* W0    = (const float*)d_in[5];
  const float* gamma = (const float*)d_in[6];
  const float* beta  = (const float*)d_in[7];
  float* out = (float*)d_out;
  float* ws  = (float*)d_ws;

  float* gt = ws;                          // H*L*D   = 2097152 floats
  float* P  = ws + 2097152;                // H*L     = 32768 floats
  float* U  = ws + 2097152 + 32768;        // H*NC*D*D= 2097152 floats
  float* Wprev = gt;                       // alias: gt dead after k_chunk

  k_gradl<<<H * L / 4, 256, 0, stream>>>(k, v, eta, W0, gamma, beta, gt);
  k_chunk<<<H * NC, 256, 0, stream>>>(q, k, gate, gt, U, P, out);
  k_scan<<<H, 256, 0, stream>>>(W0, U, P, Wprev);
  k_out<<<H * NC, 256, 0, stream>>>(q, Wprev, P, gamma, beta, out);
}

// Round 2
// 95.742 us; speedup vs baseline: 1.3810x; 1.3810x over previous
//
#include <hip/hip_runtime.h>
#include <hip/hip_bf16.h>
#include <math.h>

// Problem dims (fixed by reference setup_inputs): B=1, H=16, L=2048, D=64
// Chunked linear-recurrence decomposition, chunk C=64, NC=32.

#define H 16
#define L 2048
#define D 64
#define C 64
#define NC 32
#define P_ 68   // LDS pitch in floats: float4-aligned, stride%32=4 keeps conflicts <=2-way on reads

__device__ inline float wave_sum(float x) {
  #pragma unroll
  for (int off = 32; off > 0; off >>= 1) x += __shfl_xor(x, off, 64);
  return x;
}

// ---------------- Kernel 1: grad_l (fused LN-L2 backward), store gt = -eta*grad_l
__global__ __launch_bounds__(256) void k_gradl(
    const float* __restrict__ K, const float* __restrict__ V,
    const float* __restrict__ eta, const float* __restrict__ W0,
    const float* __restrict__ gamma, const float* __restrict__ beta,
    float* __restrict__ gt)
{
  int tid = threadIdx.x;
  int lane = tid & 63;
  int row = blockIdx.x * 4 + (tid >> 6);   // [0, H*L)
  int h = row >> 11;                       // L = 2048
  const float* w0 = W0 + h * (D * D) + lane;
  float ke = K[row * D + lane];
  float z1 = 0.f;
  #pragma unroll
  for (int d = 0; d < D; ++d) {
    float kd = __shfl(ke, d, 64);
    z1 = fmaf(kd, w0[d * D], z1);
  }
  float mu  = wave_sum(z1) * (1.f / 64.f);
  float t   = z1 - mu;
  float var = wave_sum(t * t) * (1.f / 64.f);
  float rstd = rsqrtf(var + 1e-6f);
  float xh = t * rstd;
  float ga = gamma[h * D + lane], be = beta[h * D + lane];
  float go = 2.f * (fmaf(ga, xh, be) + ke - V[row * D + lane]);
  float gxh = go * ga;
  float m1 = wave_sum(gxh) * (1.f / 64.f);
  float m2 = wave_sum(gxh * xh) * (1.f / 64.f);
  float z = (gxh - m1 - xh * m2) * rstd;
  gt[row * D + lane] = -eta[row] * z;
}

// ---------------- Kernel 2: per-chunk local work, register-tiled fp32 matmuls.
// Outputs: P[i]=exp(cl[i]), intra part of Zq (-> outIntra), chunk update U.
__global__ __launch_bounds__(256) void k_chunk(
    const float4* __restrict__ Q4, const float4* __restrict__ K4,
    const float* __restrict__ gate, const float4* __restrict__ G4,
    float* __restrict__ U, float* __restrict__ Pg, float* __restrict__ outIntra)
{
  __shared__ __align__(16) float kt[64 * P_];  // kt[d][j] : k^T
  __shared__ __align__(16) float ks[64 * P_];  // ks[j][d] : k row-major
  __shared__ __align__(16) float gs[64 * P_];  // gs[j][e] : gt row-major
  __shared__ __align__(16) float qs[64 * P_];  // qt[d][i], later st[j][i]
  __shared__ float cl[64];
  __shared__ float wj[64];

  int tid = threadIdx.x;
  int h = blockIdx.x >> 5;   // NC = 32
  int c = blockIdx.x & 31;
  int rowb = h * L + c * C;

  // stage (vectorized): 1024 float4s per tensor
  for (int idx = tid; idx < 1024; idx += 256) {
    int j = idx >> 4;
    int f = idx & 15;
    int d4 = f * 4;
    float4 kv = K4[(rowb + j) * 16 + f];
    *(float4*)&ks[j * P_ + d4] = kv;
    kt[(d4 + 0) * P_ + j] = kv.x;
    kt[(d4 + 1) * P_ + j] = kv.y;
    kt[(d4 + 2) * P_ + j] = kv.z;
    kt[(d4 + 3) * P_ + j] = kv.w;
    float4 qv = Q4[(rowb + j) * 16 + f];
    qs[(d4 + 0) * P_ + j] = qv.x;
    qs[(d4 + 1) * P_ + j] = qv.y;
    qs[(d4 + 2) * P_ + j] = qv.z;
    qs[(d4 + 3) * P_ + j] = qv.w;
    float4 gv = G4[(rowb + j) * 16 + f];
    *(float4*)&gs[j * P_ + d4] = gv;
  }
  if (tid < 64) {
    float x = logf(fmaxf(gate[rowb + tid], 1e-37f));
    #pragma unroll
    for (int off = 1; off < 64; off <<= 1) {
      float n = __shfl_up(x, off, 64);
      if (tid >= off) x += n;
    }
    cl[tid] = x;
    float c63 = __shfl(x, 63, 64);
    wj[tid] = expf(c63 - x);
    Pg[rowb + tid] = expf(x);
  }
  __syncthreads();

  int A = tid >> 4;   // 0..15
  int B = tid & 15;   // 0..15

  // Phase A: acc[r][c2] = sum_d k[4A+r][d] * q[4B+c2][d]  (= S^T pre-decay)
  float acc[4][4];
  #pragma unroll
  for (int r = 0; r < 4; ++r)
    #pragma unroll
    for (int c2 = 0; c2 < 4; ++c2) acc[r][c2] = 0.f;
  for (int d = 0; d < 64; ++d) {
    float4 kf = *(const float4*)&kt[d * P_ + 4 * A];
    float4 qf = *(const float4*)&qs[d * P_ + 4 * B];
    const float ka[4] = {kf.x, kf.y, kf.z, kf.w};
    const float qa[4] = {qf.x, qf.y, qf.z, qf.w};
    #pragma unroll
    for (int r = 0; r < 4; ++r)
      #pragma unroll
      for (int c2 = 0; c2 < 4; ++c2)
        acc[r][c2] = fmaf(ka[r], qa[c2], acc[r][c2]);
  }
  __syncthreads();   // all reads of qt done before st overwrites

  // masked decay: st[j][i] = (j<=i) ? acc*exp(cl_i - cl_j) : 0
  #pragma unroll
  for (int r = 0; r < 4; ++r) {
    int j = 4 * A + r;
    float clj = cl[j];
    float4 o;
    int i0 = 4 * B;
    o.x = (j <= i0 + 0) ? acc[r][0] * expf(cl[i0 + 0] - clj) : 0.f;
    o.y = (j <= i0 + 1) ? acc[r][1] * expf(cl[i0 + 1] - clj) : 0.f;
    o.z = (j <= i0 + 2) ? acc[r][2] * expf(cl[i0 + 2] - clj) : 0.f;
    o.w = (j <= i0 + 3) ? acc[r][3] * expf(cl[i0 + 3] - clj) : 0.f;
    *(float4*)&qs[j * P_ + i0] = o;
  }
  __syncthreads();

  // Phase 2 (fused): Intra[i][e] = sum_j st[j][i]*gs[j][e]
  //                  U[d][e]     = sum_j (wj[j]*ks[j][d])*gs[j][e]
  float fi[4][4], fu[4][4];
  #pragma unroll
  for (int r = 0; r < 4; ++r)
    #pragma unroll
    for (int c2 = 0; c2 < 4; ++c2) { fi[r][c2] = 0.f; fu[r][c2] = 0.f; }
  for (int j = 0; j < 64; ++j) {
    float4 sf = *(const float4*)&qs[j * P_ + 4 * A];
    float4 kf = *(const float4*)&ks[j * P_ + 4 * A];
    float4 gf = *(const float4*)&gs[j * P_ + 4 * B];
    float w = wj[j];
    const float sa[4] = {sf.x, sf.y, sf.z, sf.w};
    const float kw[4] = {kf.x * w, kf.y * w, kf.z * w, kf.w * w};
    const float ga[4] = {gf.x, gf.y, gf.z, gf.w};
    #pragma unroll
    for (int r = 0; r < 4; ++r)
      #pragma unroll
      for (int c2 = 0; c2 < 4; ++c2) {
        fi[r][c2] = fmaf(sa[r], ga[c2], fi[r][c2]);
        fu[r][c2] = fmaf(kw[r], ga[c2], fu[r][c2]);
      }
  }
  float* Ub = U + (h * NC + c) * (D * D);
  #pragma unroll
  for (int r = 0; r < 4; ++r) {
    float4 oi = {fi[r][0], fi[r][1], fi[r][2], fi[r][3]};
    *(float4*)&outIntra[(rowb + 4 * A + r) * D + 4 * B] = oi;
    float4 ou = {fu[r][0], fu[r][1], fu[r][2], fu[r][3]};
    *(float4*)&Ub[(4 * A + r) * D + 4 * B] = ou;
  }
}

// ---------------- Kernel 3: chunk-state scan, one thread per (head, element).
// W = Gc*W + U_c ; stores W_prev (state BEFORE chunk c).
__global__ __launch_bounds__(256) void k_scan(
    const float* __restrict__ W0, const float* __restrict__ U,
    const float* __restrict__ Pg, float* __restrict__ Wprev)
{
  int t = blockIdx.x * 256 + threadIdx.x;  // [0, H*D*D) = 65536
  int h = t >> 12;
  int e = t & 4095;
  float w = W0[t];
  #pragma unroll
  for (int c = 0; c < NC; ++c) {
    Wprev[(h * NC + c) * (D * D) + e] = w;
    w = fmaf(Pg[h * L + c * C + 63], w, U[(h * NC + c) * (D * D) + e]);
  }
}

// ---------------- Kernel 4: Zq = P*(q @ W_prev) + intra ; LN fwd ; +q
__global__ __launch_bounds__(256) void k_out(
    const float* __restrict__ Q, const float* __restrict__ Wprev,
    const float* __restrict__ Pg, const float* __restrict__ gamma,
    const float* __restrict__ beta, float* __restrict__ Out)
{
  __shared__ float Wl[D * D];
  int tid = threadIdx.x;
  int lane = tid & 63;
  int wv = tid >> 6;
  int h = blockIdx.x >> 5;
  int c = blockIdx.x & 31;
  int rowb = h * L + c * C;
  const float* wp = Wprev + (h * NC + c) * (D * D);
  for (int idx = tid; idx < D * D; idx += 256) Wl[idx] = wp[idx];
  __syncthreads();
  float ga = gamma[h * D + lane], be = beta[h * D + lane];
  for (int i0 = 0; i0 < 16; ++i0) {
    int i = wv * 16 + i0;
    int row = rowb + i;
    float qe = Q[row * D + lane];
    float acc = 0.f;
    #pragma unroll
    for (int d = 0; d < D; ++d) {
      float qd = __shfl(qe, d, 64);
      acc = fmaf(qd, Wl[d * D + lane], acc);
    }
    float zq = fmaf(Pg[row], acc, Out[row * D + lane]);
    float mu  = wave_sum(zq) * (1.f / 64.f);
    float t   = zq - mu;
    float var = wave_sum(t * t) * (1.f / 64.f);
    float xh = t * rsqrtf(var + 1e-6f);
    Out[row * D + lane] = fmaf(ga, xh, be) + qe;
  }
}

extern "C" void kernel_launch(void* const* d_in, const int* in_sizes, int n_in,
                              void* d_out, int out_size, void* d_ws, size_t ws_size,
                              hipStream_t stream) {
  const float* q     = (const float*)d_in[0];
  const float* k     = (const float*)d_in[1];
  const float* v     = (const float*)d_in[2];
  const float* gate  = (const float*)d_in[3];
  const float* eta   = (const float*)d_in[4];
  const float* W0    = (const float*)d_in[5];
  const float* gamma = (const float*)d_in[6];
  const float* beta  = (const float*)d_in[7];
  float* out = (float*)d_out;
  float* ws  = (float*)d_ws;

  float* gt = ws;                          // H*L*D    = 2097152 floats
  float* Pg = ws + 2097152;                // H*L      = 32768 floats
  float* U  = ws + 2097152 + 32768;        // H*NC*D*D = 2097152 floats
  float* Wprev = gt;                       // alias: gt dead after k_chunk

  k_gradl<<<H * L / 4, 256, 0, stream>>>(k, v, eta, W0, gamma, beta, gt);
  k_chunk<<<H * NC, 256, 0, stream>>>((const float4*)q, (const float4*)k, gate,
                                      (const float4*)gt, U, Pg, out);
  k_scan<<<H * D * D / 256, 256, 0, stream>>>(W0, U, Pg, Wprev);
  k_out<<<H * NC, 256, 0, stream>>>(q, Wprev, Pg, gamma, beta, out);
}

// Round 3
// 41.498 us; speedup vs baseline: 3.1862x; 2.3071x over previous
//
#include <hip/hip_runtime.h>
#include <hip/hip_bf16.h>
#include <math.h>

// B=1, H=16, L=2048, D=64. Chunked gated-linear-recurrence, chunk C=64, NC=32.
// All LDS tiles are float4-granule XOR-swizzled: element (row, f-granule) lives at
// granule index SW(row,f) = row*16 + (f ^ ((row>>2)&15)). Every read/write pattern
// used below is <=2-way bank aliasing (free on CDNA4).

#define H 16
#define L 2048
#define D 64
#define C 64
#define NC 32

#define SW(row, f) (((row) << 4) + ((f) ^ (((row) >> 2) & 15)))

__device__ inline void red16(float& x) {
  x += __shfl_xor(x, 1, 64);
  x += __shfl_xor(x, 2, 64);
  x += __shfl_xor(x, 4, 64);
  x += __shfl_xor(x, 8, 64);
}

// ---------------- Kernel 1 (fused): per-chunk gradl + QK^T + decay + Intra + U.
// Thread (A,B) = (tid>>4, tid&15) owns the 4x4 tile rows 4A..4A+3, cols 4B..4B+3.
__global__ __launch_bounds__(256) void k_chunk(
    const float4* __restrict__ Q4, const float4* __restrict__ K4,
    const float4* __restrict__ V4, const float* __restrict__ gate,
    const float* __restrict__ eta, const float4* __restrict__ W04,
    const float4* __restrict__ gamma4, const float4* __restrict__ beta4,
    float4* __restrict__ U4, float* __restrict__ Pg, float4* __restrict__ Out4)
{
  __shared__ float4 ks4[1024];   // k rows (swizzled)
  __shared__ float4 qs4[1024];   // q rows, later S^T (st[j][i])
  __shared__ float4 gs4[1024];   // W0, later gt rows
  __shared__ float cl[64], wj[64];

  int tid = threadIdx.x;
  int h = blockIdx.x >> 5, c = blockIdx.x & 31;
  int rowb = h * L + c * C;

  for (int idx = tid; idx < 1024; idx += 256) {
    int row = idx >> 4, f = idx & 15;
    ks4[SW(row, f)] = K4[(rowb + row) * 16 + f];
    qs4[SW(row, f)] = Q4[(rowb + row) * 16 + f];
    gs4[SW(row, f)] = W04[h * 1024 + idx];
  }
  if (tid < 64) {
    float x = logf(fmaxf(gate[rowb + tid], 1e-37f));
    #pragma unroll
    for (int off = 1; off < 64; off <<= 1) {
      float n = __shfl_up(x, off, 64);
      if (tid >= off) x += n;
    }
    cl[tid] = x;
    float c63 = __shfl(x, 63, 64);
    wj[tid] = expf(c63 - x);
    Pg[rowb + tid] = expf(x);
  }
  __syncthreads();

  int A = tid >> 4, B = tid & 15;

  // Fused matmuls over d: acc2[r][cc] = k_{4A+r} . q_{4B+cc}   (QK^T, pre-decay)
  //                       accz[r][cc] = (K @ W0)[4A+r][4B+cc]  (Z1)
  float acc2[4][4], accz[4][4];
  #pragma unroll
  for (int r = 0; r < 4; ++r)
    #pragma unroll
    for (int cc = 0; cc < 4; ++cc) { acc2[r][cc] = 0.f; accz[r][cc] = 0.f; }

  for (int dc = 0; dc < 16; ++dc) {
    float ka[4][4], qa[4][4], wa[4][4];
    #pragma unroll
    for (int r = 0; r < 4; ++r) {
      float4 t = ks4[SW(4 * A + r, dc)];
      ka[r][0] = t.x; ka[r][1] = t.y; ka[r][2] = t.z; ka[r][3] = t.w;
    }
    #pragma unroll
    for (int cc = 0; cc < 4; ++cc) {
      float4 t = qs4[SW(4 * B + cc, dc)];
      qa[cc][0] = t.x; qa[cc][1] = t.y; qa[cc][2] = t.z; qa[cc][3] = t.w;
    }
    #pragma unroll
    for (int dd = 0; dd < 4; ++dd) {
      float4 t = gs4[SW(4 * dc + dd, B)];
      wa[dd][0] = t.x; wa[dd][1] = t.y; wa[dd][2] = t.z; wa[dd][3] = t.w;
    }
    #pragma unroll
    for (int r = 0; r < 4; ++r)
      #pragma unroll
      for (int cc = 0; cc < 4; ++cc) {
        float s = acc2[r][cc];
        s = fmaf(ka[r][0], qa[cc][0], s);
        s = fmaf(ka[r][1], qa[cc][1], s);
        s = fmaf(ka[r][2], qa[cc][2], s);
        s = fmaf(ka[r][3], qa[cc][3], s);
        acc2[r][cc] = s;
        float z = accz[r][cc];
        z = fmaf(ka[r][0], wa[0][cc], z);
        z = fmaf(ka[r][1], wa[1][cc], z);
        z = fmaf(ka[r][2], wa[2][cc], z);
        z = fmaf(ka[r][3], wa[3][cc], z);
        accz[r][cc] = z;
      }
  }

  // LN-L2 backward per row (16 lanes per row, 4 elems each); gt -> accz in place.
  float4 ga4 = gamma4[h * 16 + B];
  float4 be4 = beta4[h * 16 + B];
  const float ga[4] = {ga4.x, ga4.y, ga4.z, ga4.w};
  const float be[4] = {be4.x, be4.y, be4.z, be4.w};
  #pragma unroll
  for (int r = 0; r < 4; ++r) {
    int row = 4 * A + r;
    float4 kvv = ks4[SW(row, B)];
    float4 vv  = V4[(rowb + row) * 16 + B];
    const float kk[4] = {kvv.x, kvv.y, kvv.z, kvv.w};
    const float va[4] = {vv.x, vv.y, vv.z, vv.w};
    float er = eta[rowb + row];
    float s1 = accz[r][0] + accz[r][1] + accz[r][2] + accz[r][3];
    red16(s1);
    float mu = s1 * (1.f / 64.f);
    float dv[4], s2 = 0.f;
    #pragma unroll
    for (int cc = 0; cc < 4; ++cc) { dv[cc] = accz[r][cc] - mu; s2 += dv[cc] * dv[cc]; }
    red16(s2);
    float rstd = rsqrtf(s2 * (1.f / 64.f) + 1e-6f);
    float xh[4], gxh[4], t1 = 0.f, t2 = 0.f;
    #pragma unroll
    for (int cc = 0; cc < 4; ++cc) {
      xh[cc] = dv[cc] * rstd;
      float go = 2.f * (fmaf(ga[cc], xh[cc], be[cc]) + kk[cc] - va[cc]);
      gxh[cc] = go * ga[cc];
      t1 += gxh[cc];
      t2 += gxh[cc] * xh[cc];
    }
    red16(t1);
    red16(t2);
    float m1 = t1 * (1.f / 64.f), m2 = t2 * (1.f / 64.f);
    #pragma unroll
    for (int cc = 0; cc < 4; ++cc)
      accz[r][cc] = -er * (gxh[cc] - m1 - xh[cc] * m2) * rstd;
  }
  __syncthreads();   // all reads of gs(W0) and qs(q) done

  // Write gt rows into gs; masked-decay S^T into qs: st[j][i] = (j<=i)?A*exp(cl_i-cl_j):0
  #pragma unroll
  for (int r = 0; r < 4; ++r) {
    int j = 4 * A + r;
    float4 g = {accz[r][0], accz[r][1], accz[r][2], accz[r][3]};
    gs4[SW(j, B)] = g;
    float clj = cl[j];
    float4 o;
    o.x = (j <= 4 * B + 0) ? acc2[r][0] * expf(cl[4 * B + 0] - clj) : 0.f;
    o.y = (j <= 4 * B + 1) ? acc2[r][1] * expf(cl[4 * B + 1] - clj) : 0.f;
    o.z = (j <= 4 * B + 2) ? acc2[r][2] * expf(cl[4 * B + 2] - clj) : 0.f;
    o.w = (j <= 4 * B + 3) ? acc2[r][3] * expf(cl[4 * B + 3] - clj) : 0.f;
    qs4[SW(j, B)] = o;
  }
  __syncthreads();

  // Phase 2 (fused): Intra[i][e] = sum_j st[j][i]*gt[j][e]
  //                  U[d][e]     = sum_j wj[j]*k[j][d]*gt[j][e]
  float fi[4][4], fu[4][4];
  #pragma unroll
  for (int r = 0; r < 4; ++r)
    #pragma unroll
    for (int cc = 0; cc < 4; ++cc) { fi[r][cc] = 0.f; fu[r][cc] = 0.f; }
  #pragma unroll 8
  for (int j = 0; j < 64; ++j) {
    float4 sf = qs4[SW(j, A)];
    float4 kf = ks4[SW(j, A)];
    float4 gf = gs4[SW(j, B)];
    float w = wj[j];
    const float sa[4] = {sf.x, sf.y, sf.z, sf.w};
    const float kz[4] = {kf.x, kf.y, kf.z, kf.w};
    const float gg[4] = {gf.x, gf.y, gf.z, gf.w};
    const float wg[4] = {w * gf.x, w * gf.y, w * gf.z, w * gf.w};
    #pragma unroll
    for (int r = 0; r < 4; ++r)
      #pragma unroll
      for (int cc = 0; cc < 4; ++cc) {
        fi[r][cc] = fmaf(sa[r], gg[cc], fi[r][cc]);
        fu[r][cc] = fmaf(kz[r], wg[cc], fu[r][cc]);
      }
  }
  float4* Ub = U4 + (h * NC + c) * 1024;
  #pragma unroll
  for (int r = 0; r < 4; ++r) {
    int row = 4 * A + r;
    float4 oi = {fi[r][0], fi[r][1], fi[r][2], fi[r][3]};
    Out4[(rowb + row) * 16 + B] = oi;
    float4 ou = {fu[r][0], fu[r][1], fu[r][2], fu[r][3]};
    Ub[row * 16 + B] = ou;
  }
}

// ---------------- Kernel 2: chunk-state scan, one thread per (head, element).
__global__ __launch_bounds__(256) void k_scan(
    const float* __restrict__ W0, const float* __restrict__ U,
    const float* __restrict__ Pg, float* __restrict__ Wprev)
{
  int t = blockIdx.x * 256 + threadIdx.x;  // [0, H*D*D)
  int h = t >> 12;
  int e = t & 4095;
  float w = W0[t];
  #pragma unroll
  for (int c = 0; c < NC; ++c) {
    Wprev[(h * NC + c) * (D * D) + e] = w;
    w = fmaf(Pg[h * L + c * C + 63], w, U[(h * NC + c) * (D * D) + e]);
  }
}

// ---------------- Kernel 3: Zq = P*(q @ W_prev) + intra ; LN fwd ; +q
__global__ __launch_bounds__(256) void k_out(
    const float4* __restrict__ Q4, const float4* __restrict__ Wprev4,
    const float* __restrict__ Pg, const float4* __restrict__ gamma4,
    const float4* __restrict__ beta4, float4* __restrict__ Out4)
{
  __shared__ float4 Wl4[1024];
  __shared__ float4 qs4[1024];
  int tid = threadIdx.x;
  int h = blockIdx.x >> 5, c = blockIdx.x & 31;
  int rowb = h * L + c * C;
  const float4* wp = Wprev4 + (h * NC + c) * 1024;
  for (int idx = tid; idx < 1024; idx += 256) {
    int row = idx >> 4, f = idx & 15;
    Wl4[SW(row, f)] = wp[idx];
    qs4[SW(row, f)] = Q4[(rowb + row) * 16 + f];
  }
  __syncthreads();

  int A = tid >> 4, B = tid & 15;
  float acc[4][4];
  #pragma unroll
  for (int r = 0; r < 4; ++r)
    #pragma unroll
    for (int cc = 0; cc < 4; ++cc) acc[r][cc] = 0.f;

  for (int dc = 0; dc < 16; ++dc) {
    float qa[4][4], wa[4][4];
    #pragma unroll
    for (int r = 0; r < 4; ++r) {
      float4 t = qs4[SW(4 * A + r, dc)];
      qa[r][0] = t.x; qa[r][1] = t.y; qa[r][2] = t.z; qa[r][3] = t.w;
    }
    #pragma unroll
    for (int dd = 0; dd < 4; ++dd) {
      float4 t = Wl4[SW(4 * dc + dd, B)];
      wa[dd][0] = t.x; wa[dd][1] = t.y; wa[dd][2] = t.z; wa[dd][3] = t.w;
    }
    #pragma unroll
    for (int r = 0; r < 4; ++r)
      #pragma unroll
      for (int cc = 0; cc < 4; ++cc) {
        float s = acc[r][cc];
        s = fmaf(qa[r][0], wa[0][cc], s);
        s = fmaf(qa[r][1], wa[1][cc], s);
        s = fmaf(qa[r][2], wa[2][cc], s);
        s = fmaf(qa[r][3], wa[3][cc], s);
        acc[r][cc] = s;
      }
  }

  float4 ga4 = gamma4[h * 16 + B];
  float4 be4 = beta4[h * 16 + B];
  const float ga[4] = {ga4.x, ga4.y, ga4.z, ga4.w};
  const float be[4] = {be4.x, be4.y, be4.z, be4.w};
  #pragma unroll
  for (int r = 0; r < 4; ++r) {
    int row = rowb + 4 * A + r;
    float pr = Pg[row];
    float4 io = Out4[row * 16 + B];
    float zq[4] = {fmaf(pr, acc[r][0], io.x), fmaf(pr, acc[r][1], io.y),
                   fmaf(pr, acc[r][2], io.z), fmaf(pr, acc[r][3], io.w)};
    float s1 = zq[0] + zq[1] + zq[2] + zq[3];
    red16(s1);
    float mu = s1 * (1.f / 64.f);
    float dv[4], s2 = 0.f;
    #pragma unroll
    for (int cc = 0; cc < 4; ++cc) { dv[cc] = zq[cc] - mu; s2 += dv[cc] * dv[cc]; }
    red16(s2);
    float rstd = rsqrtf(s2 * (1.f / 64.f) + 1e-6f);
    float4 qres = qs4[SW(4 * A + r, B)];
    float4 o;
    o.x = fmaf(ga[0], dv[0] * rstd, be[0]) + qres.x;
    o.y = fmaf(ga[1], dv[1] * rstd, be[1]) + qres.y;
    o.z = fmaf(ga[2], dv[2] * rstd, be[2]) + qres.z;
    o.w = fmaf(ga[3], dv[3] * rstd, be[3]) + qres.w;
    Out4[row * 16 + B] = o;
  }
}

extern "C" void kernel_launch(void* const* d_in, const int* in_sizes, int n_in,
                              void* d_out, int out_size, void* d_ws, size_t ws_size,
                              hipStream_t stream) {
  const float* q     = (const float*)d_in[0];
  const float* k     = (const float*)d_in[1];
  const float* v     = (const float*)d_in[2];
  const float* gate  = (const float*)d_in[3];
  const float* eta   = (const float*)d_in[4];
  const float* W0    = (const float*)d_in[5];
  const float* gamma = (const float*)d_in[6];
  const float* beta  = (const float*)d_in[7];
  float* out = (float*)d_out;
  float* ws  = (float*)d_ws;

  float* Pg    = ws;                       // H*L      = 32768 floats
  float* U     = ws + 32768;               // H*NC*D*D = 2097152 floats
  float* Wprev = ws + 32768 + 2097152;     // H*NC*D*D = 2097152 floats

  k_chunk<<<H * NC, 256, 0, stream>>>(
      (const float4*)q, (const float4*)k, (const float4*)v, gate, eta,
      (const float4*)W0, (const float4*)gamma, (const float4*)beta,
      (float4*)U, Pg, (float4*)out);
  k_scan<<<H * D * D / 256, 256, 0, stream>>>(W0, U, Pg, Wprev);
  k_out<<<H * NC, 256, 0, stream>>>(
      (const float4*)q, (const float4*)Wprev, Pg,
      (const float4*)gamma, (const float4*)beta, (float4*)out);
}

// Round 6
// 39.463 us; speedup vs baseline: 3.3505x; 1.0516x over previous
//
#include <hip/hip_runtime.h>
#include <hip/hip_bf16.h>
#include <math.h>

// B=1, H=16, L=2048, D=64. Chunked gated recurrence, chunk C=64, NC=32.
// All 64^3 matmuls via v_mfma_f32_16x16x32_bf16 with FULL hi/lo split-bf16
// (3-MFMA emulation, rel err ~2^-17) on EVERY operand: LN row-normalization
// amplifies relative rounding by |mean|/|std|, so single-bf16 anywhere fails.
// LDS tiles: bf16 [64 rows][128B], XOR-swizzled (byte ^= (row&7)<<4).
// A row-major [M][K], B transposed [N][K]: every fragment is one ds_read_b128
// (lane l -> row (l&15)+16*tile, 8 contiguous k at byte 16*(l>>4) + 64*khalf).
// C/D: row = 4*(l>>4)+reg, col = l&15 (m89-verified).

#define H 16
#define L 2048
#define D 64
#define C 64
#define NC 32

typedef short s8v __attribute__((ext_vector_type(8)));
typedef short s4v __attribute__((ext_vector_type(4)));
typedef float f4v __attribute__((ext_vector_type(4)));

__device__ inline unsigned short f2bf(float x) {
  unsigned u = __float_as_uint(x);
  return (unsigned short)((u + 0x7fffu + ((u >> 16) & 1u)) >> 16);
}
__device__ inline float bf2f(unsigned short s) { return __uint_as_float(((unsigned)s) << 16); }

__device__ inline int swz(int row, int colByte) { return row * 128 + (colByte ^ ((row & 7) << 4)); }

__device__ inline s8v ld8(const short* base, int row, int colByte) {
  return *(const s8v*)((const char*)base + swz(row, colByte));
}
__device__ inline void st4(short* base, int row, int colByte, s4v v) {
  *(s4v*)((char*)base + swz(row, colByte)) = v;
}
__device__ inline void st1(short* base, int row, int colByte, unsigned short v) {
  *(short*)((char*)base + swz(row, colByte)) = (short)v;
}

__device__ inline void red16(float& x) {
  x += __shfl_xor(x, 1, 64);
  x += __shfl_xor(x, 2, 64);
  x += __shfl_xor(x, 4, 64);
  x += __shfl_xor(x, 8, 64);
}

__device__ inline f4v MM(s8v a, s8v b, f4v c) {
  return __builtin_amdgcn_mfma_f32_16x16x32_bf16(a, b, c, 0, 0, 0);
}

// 3-MFMA split product: (Ah+Al)(Bh+Bl) ~= Ah*Bh + Ah*Bl + Al*Bh
__device__ inline f4v MM3(s8v ah, s8v al, s8v bh, s8v bl, f4v c) {
  c = MM(ah, bh, c);
  c = MM(ah, bl, c);
  c = MM(al, bh, c);
  return c;
}

// ---------------- Kernel 1: per-chunk gradl + QK^T + decay + Intra + U^T.
__global__ __launch_bounds__(256) void k_chunk(
    const float4* __restrict__ Q4, const float4* __restrict__ K4,
    const float* __restrict__ Kg, const float* __restrict__ Vg,
    const float* __restrict__ gate, const float* __restrict__ eta,
    const float4* __restrict__ W04, const float* __restrict__ gamma,
    const float* __restrict__ beta,
    float* __restrict__ Ut, float* __restrict__ Pg, float* __restrict__ Out)
{
  __shared__ __align__(16) short Qhi[4096];  // q rows hi (A M1); after bar2: S hi
  __shared__ __align__(16) short Qlo[4096];  // q rows lo;        after bar2: S lo
  __shared__ __align__(16) short Khi[4096];  // k rows hi (A M2; B M1)
  __shared__ __align__(16) short Klo[4096];  // k rows lo
  __shared__ __align__(16) short KtH[4096];  // (wj*k)^T [d][j] hi (B M4)
  __shared__ __align__(16) short KtL[4096];  // (wj*k)^T [d][j] lo
  __shared__ __align__(16) short W0h[4096];  // W0^T [e][d] hi (B M2)
  __shared__ __align__(16) short W0l[4096];  // W0^T [e][d] lo
  __shared__ __align__(16) short GtH[4096];  // gt^T [e][j] hi (B M3; A M4)
  __shared__ __align__(16) short GtL[4096];  // gt^T [e][j] lo
  __shared__ float cl[64], wj[64];

  int tid = threadIdx.x;
  int h = blockIdx.x >> 5, c = blockIdx.x & 31;
  int rowb = h * L + c * C;

  // ---- gate log-cumsum first (staging needs wj)
  if (tid < 64) {
    float x = logf(fmaxf(gate[rowb + tid], 1e-37f));
    #pragma unroll
    for (int off = 1; off < 64; off <<= 1) {
      float n = __shfl_up(x, off, 64);
      if (tid >= off) x += n;
    }
    cl[tid] = x;
    float c63 = __shfl(x, 63, 64);
    wj[tid] = expf(c63 - x);
    Pg[rowb + tid] = expf(x);
  }
  __syncthreads();

  // ---- stage: fp32 -> bf16 hi/lo for q, k, wj*k^T, W0^T
  for (int idx = tid; idx < 1024; idx += 256) {
    int row = idx >> 4, g4 = idx & 15, cb = g4 * 8;
    float4 kv = K4[(rowb + row) * 16 + g4];
    float ke[4] = {kv.x, kv.y, kv.z, kv.w};
    float wr = wj[row];
    s4v khv, klv;
    #pragma unroll
    for (int e = 0; e < 4; ++e) {
      unsigned short hb = f2bf(ke[e]);
      khv[e] = (short)hb;
      klv[e] = (short)f2bf(ke[e] - bf2f(hb));
      float wk = ke[e] * wr;
      unsigned short wh = f2bf(wk);
      st1(KtH, 4 * g4 + e, 2 * row, wh);
      st1(KtL, 4 * g4 + e, 2 * row, f2bf(wk - bf2f(wh)));
    }
    st4(Khi, row, cb, khv);
    st4(Klo, row, cb, klv);
    float4 qv = Q4[(rowb + row) * 16 + g4];
    float qe[4] = {qv.x, qv.y, qv.z, qv.w};
    s4v qh, ql;
    #pragma unroll
    for (int e = 0; e < 4; ++e) {
      unsigned short hb = f2bf(qe[e]);
      qh[e] = (short)hb;
      ql[e] = (short)f2bf(qe[e] - bf2f(hb));
    }
    st4(Qhi, row, cb, qh);
    st4(Qlo, row, cb, ql);
    float4 wv = W04[h * 1024 + idx];
    float we[4] = {wv.x, wv.y, wv.z, wv.w};
    #pragma unroll
    for (int e = 0; e < 4; ++e) {
      unsigned short hb = f2bf(we[e]);
      st1(W0h, 4 * g4 + e, 2 * row, hb);
      st1(W0l, 4 * g4 + e, 2 * row, f2bf(we[e] - bf2f(hb)));
    }
  }
  __syncthreads();

  int R = tid >> 6, l = tid & 63, g = l >> 4, c16 = l & 15;
  int arow = 16 * R + c16;
  int kb0 = 16 * g, kb1 = 64 + 16 * g;

  // ---- M1: S[i][j] = q_i . k_j  (split x split)
  s8v aQh0 = ld8(Qhi, arow, kb0), aQh1 = ld8(Qhi, arow, kb1);
  s8v aQl0 = ld8(Qlo, arow, kb0), aQl1 = ld8(Qlo, arow, kb1);
  f4v accS[4];
  #pragma unroll
  for (int ct = 0; ct < 4; ++ct) {
    int br = 16 * ct + c16;
    f4v a = {0.f, 0.f, 0.f, 0.f};
    a = MM3(aQh0, aQl0, ld8(Khi, br, kb0), ld8(Klo, br, kb0), a);
    a = MM3(aQh1, aQl1, ld8(Khi, br, kb1), ld8(Klo, br, kb1), a);
    accS[ct] = a;
  }

  // ---- M2: Z1 = K @ W0  (split x split)
  s8v aKh0 = ld8(Khi, arow, kb0), aKh1 = ld8(Khi, arow, kb1);
  s8v aKl0 = ld8(Klo, arow, kb0), aKl1 = ld8(Klo, arow, kb1);
  f4v accZ[4];
  #pragma unroll
  for (int ct = 0; ct < 4; ++ct) {
    int br = 16 * ct + c16;
    f4v a = {0.f, 0.f, 0.f, 0.f};
    a = MM3(aKh0, aKl0, ld8(W0h, br, kb0), ld8(W0l, br, kb0), a);
    a = MM3(aKh1, aKl1, ld8(W0h, br, kb1), ld8(W0l, br, kb1), a);
    accZ[ct] = a;
  }

  // ---- LN-L2 backward (rows jr = 16R+4g+r, cols e = 16ct+c16), fp32 k,v.
  float ga[4], be[4];
  #pragma unroll
  for (int ct = 0; ct < 4; ++ct) {
    ga[ct] = gamma[h * 64 + 16 * ct + c16];
    be[ct] = beta[h * 64 + 16 * ct + c16];
  }
  #pragma unroll
  for (int r = 0; r < 4; ++r) {
    int jr = 16 * R + 4 * g + r;
    int grow = (rowb + jr) * 64;
    float kk[4], vv[4];
    #pragma unroll
    for (int ct = 0; ct < 4; ++ct) {
      kk[ct] = Kg[grow + 16 * ct + c16];
      vv[ct] = Vg[grow + 16 * ct + c16];
    }
    float s1 = accZ[0][r] + accZ[1][r] + accZ[2][r] + accZ[3][r];
    red16(s1);
    float mu = s1 * (1.f / 64.f);
    float dv[4], s2 = 0.f;
    #pragma unroll
    for (int ct = 0; ct < 4; ++ct) { dv[ct] = accZ[ct][r] - mu; s2 += dv[ct] * dv[ct]; }
    red16(s2);
    float rstd = rsqrtf(s2 * (1.f / 64.f) + 1e-6f);
    float xh[4], gxh[4], t1 = 0.f, t2 = 0.f;
    #pragma unroll
    for (int ct = 0; ct < 4; ++ct) {
      xh[ct] = dv[ct] * rstd;
      float go = 2.f * (fmaf(ga[ct], xh[ct], be[ct]) + kk[ct] - vv[ct]);
      gxh[ct] = go * ga[ct];
      t1 += gxh[ct];
      t2 += gxh[ct] * xh[ct];
    }
    red16(t1);
    red16(t2);
    float m1 = t1 * (1.f / 64.f), m2 = t2 * (1.f / 64.f);
    float er = eta[rowb + jr];
    #pragma unroll
    for (int ct = 0; ct < 4; ++ct) {
      float gtv = -er * (gxh[ct] - m1 - xh[ct] * m2) * rstd;
      unsigned short hb = f2bf(gtv);
      st1(GtH, 16 * ct + c16, 2 * jr, hb);
      st1(GtL, 16 * ct + c16, 2 * jr, f2bf(gtv - bf2f(hb)));
    }
  }
  __syncthreads();   // GtH/GtL complete; q tiles dead -> reuse for split S

  // ---- decay+mask S, split store: hi -> Qhi, lo -> Qlo (wave-own rows only)
  float cli[4];
  #pragma unroll
  for (int r = 0; r < 4; ++r) cli[r] = cl[16 * R + 4 * g + r];
  #pragma unroll
  for (int ct = 0; ct < 4; ++ct) {
    int j = 16 * ct + c16;
    float clj = cl[j];
    #pragma unroll
    for (int r = 0; r < 4; ++r) {
      int i = 16 * R + 4 * g + r;
      float s = (j <= i) ? accS[ct][r] * expf(cli[r] - clj) : 0.f;
      unsigned short hb = f2bf(s);
      st1(Qhi, i, 2 * j, hb);
      st1(Qlo, i, 2 * j, f2bf(s - bf2f(hb)));
    }
  }

  // ---- M3: Intra[i][e] = sum_j S[i][j] gt[j][e]  (split x split)
  s8v aSh0 = ld8(Qhi, arow, kb0), aSh1 = ld8(Qhi, arow, kb1);
  s8v aSl0 = ld8(Qlo, arow, kb0), aSl1 = ld8(Qlo, arow, kb1);
  #pragma unroll
  for (int ct = 0; ct < 4; ++ct) {
    int br = 16 * ct + c16;
    f4v a = {0.f, 0.f, 0.f, 0.f};
    a = MM3(aSh0, aSl0, ld8(GtH, br, kb0), ld8(GtL, br, kb0), a);
    a = MM3(aSh1, aSl1, ld8(GtH, br, kb1), ld8(GtL, br, kb1), a);
    #pragma unroll
    for (int r = 0; r < 4; ++r)
      Out[(rowb + 16 * R + 4 * g + r) * 64 + 16 * ct + c16] = a[r];
  }

  // ---- M4: U^T[e][d] = sum_j gt[j][e] * (wj[j] k[j][d])  (split x split)
  float* ub = Ut + (h * NC + c) * 4096;
  s8v aGh0 = ld8(GtH, arow, kb0), aGh1 = ld8(GtH, arow, kb1);
  s8v aGl0 = ld8(GtL, arow, kb0), aGl1 = ld8(GtL, arow, kb1);
  #pragma unroll
  for (int ct = 0; ct < 4; ++ct) {
    int br = 16 * ct + c16;
    f4v a = {0.f, 0.f, 0.f, 0.f};
    a = MM3(aGh0, aGl0, ld8(KtH, br, kb0), ld8(KtL, br, kb0), a);
    a = MM3(aGh1, aGl1, ld8(KtH, br, kb1), ld8(KtL, br, kb1), a);
    #pragma unroll
    for (int r = 0; r < 4; ++r)
      ub[(16 * R + 4 * g + r) * 64 + 16 * ct + c16] = a[r];
  }
}

// ---------------- Kernel 2: chunk-state scan on transposed state (float4 lanes).
__global__ __launch_bounds__(256) void k_scan(
    const float* __restrict__ W0, const float4* __restrict__ Ut4,
    const float* __restrict__ Pg, float4* __restrict__ Wpt4)
{
  int t4 = blockIdx.x * 256 + threadIdx.x;   // [0, 16384)
  int h = t4 >> 10;
  int e4 = t4 & 1023;
  int erow = e4 >> 4;
  int d0 = (e4 & 15) * 4;
  const float* w0 = W0 + h * 4096;
  float4 w;
  w.x = w0[(d0 + 0) * 64 + erow];
  w.y = w0[(d0 + 1) * 64 + erow];
  w.z = w0[(d0 + 2) * 64 + erow];
  w.w = w0[(d0 + 3) * 64 + erow];
  for (int c2 = 0; c2 < NC; ++c2) {
    int off = (h * NC + c2) * 1024 + e4;
    Wpt4[off] = w;
    float gc = Pg[h * L + c2 * 64 + 63];
    float4 u = Ut4[off];
    w.x = fmaf(gc, w.x, u.x);
    w.y = fmaf(gc, w.y, u.y);
    w.z = fmaf(gc, w.z, u.z);
    w.w = fmaf(gc, w.w, u.w);
  }
}

// ---------------- Kernel 3: Zq = Pg*(q @ Wprev) + Intra ; LN fwd ; +q
__global__ __launch_bounds__(256) void k_out(
    const float4* __restrict__ Q4, const float* __restrict__ Qg,
    const float4* __restrict__ Wpt4, const float* __restrict__ Pg,
    const float* __restrict__ gamma, const float* __restrict__ beta,
    float* __restrict__ Out)
{
  __shared__ __align__(16) short Qhi[4096];
  __shared__ __align__(16) short Qlo[4096];
  __shared__ __align__(16) short Whi[4096];  // Wprev^T [e][d] hi
  __shared__ __align__(16) short Wlo[4096];  // Wprev^T [e][d] lo
  int tid = threadIdx.x;
  int h = blockIdx.x >> 5, c = blockIdx.x & 31;
  int rowb = h * L + c * C;
  for (int idx = tid; idx < 1024; idx += 256) {
    int row = idx >> 4, g4 = idx & 15, cb = g4 * 8;
    float4 qv = Q4[(rowb + row) * 16 + g4];
    float qe[4] = {qv.x, qv.y, qv.z, qv.w};
    s4v qh, ql;
    #pragma unroll
    for (int e = 0; e < 4; ++e) {
      unsigned short hb = f2bf(qe[e]);
      qh[e] = (short)hb;
      ql[e] = (short)f2bf(qe[e] - bf2f(hb));
    }
    st4(Qhi, row, cb, qh);
    st4(Qlo, row, cb, ql);
    float4 wv = Wpt4[(h * NC + c) * 1024 + idx];
    float we[4] = {wv.x, wv.y, wv.z, wv.w};
    s4v wh, wl;
    #pragma unroll
    for (int e = 0; e < 4; ++e) {
      unsigned short hb = f2bf(we[e]);
      wh[e] = (short)hb;
      wl[e] = (short)f2bf(we[e] - bf2f(hb));
    }
    st4(Whi, row, cb, wh);
    st4(Wlo, row, cb, wl);
  }
  __syncthreads();

  int R = tid >> 6, l = tid & 63, g = l >> 4, c16 = l & 15;
  int arow = 16 * R + c16;
  int kb0 = 16 * g, kb1 = 64 + 16 * g;
  s8v ah0 = ld8(Qhi, arow, kb0), ah1 = ld8(Qhi, arow, kb1);
  s8v al0 = ld8(Qlo, arow, kb0), al1 = ld8(Qlo, arow, kb1);
  f4v acc[4];
  #pragma unroll
  for (int ct = 0; ct < 4; ++ct) {
    int br = 16 * ct + c16;
    f4v a = {0.f, 0.f, 0.f, 0.f};
    a = MM3(ah0, al0, ld8(Whi, br, kb0), ld8(Wlo, br, kb0), a);
    a = MM3(ah1, al1, ld8(Whi, br, kb1), ld8(Wlo, br, kb1), a);
    acc[ct] = a;
  }
  float ga[4], be[4];
  #pragma unroll
  for (int ct = 0; ct < 4; ++ct) {
    ga[ct] = gamma[h * 64 + 16 * ct + c16];
    be[ct] = beta[h * 64 + 16 * ct + c16];
  }
  #pragma unroll
  for (int r = 0; r < 4; ++r) {
    int row = rowb + 16 * R + 4 * g + r;
    float pr = Pg[row];
    float zq[4];
    #pragma unroll
    for (int ct = 0; ct < 4; ++ct)
      zq[ct] = fmaf(pr, acc[ct][r], Out[row * 64 + 16 * ct + c16]);
    float s1 = zq[0] + zq[1] + zq[2] + zq[3];
    red16(s1);
    float mu = s1 * (1.f / 64.f);
    float dv[4], s2 = 0.f;
    #pragma unroll
    for (int ct = 0; ct < 4; ++ct) { dv[ct] = zq[ct] - mu; s2 += dv[ct] * dv[ct]; }
    red16(s2);
    float rstd = rsqrtf(s2 * (1.f / 64.f) + 1e-6f);
    #pragma unroll
    for (int ct = 0; ct < 4; ++ct) {
      float o = fmaf(ga[ct], dv[ct] * rstd, be[ct]) + Qg[row * 64 + 16 * ct + c16];
      Out[row * 64 + 16 * ct + c16] = o;
    }
  }
}

extern "C" void kernel_launch(void* const* d_in, const int* in_sizes, int n_in,
                              void* d_out, int out_size, void* d_ws, size_t ws_size,
                              hipStream_t stream) {
  const float* q     = (const float*)d_in[0];
  const float* k     = (const float*)d_in[1];
  const float* v     = (const float*)d_in[2];
  const float* gate  = (const float*)d_in[3];
  const float* eta   = (const float*)d_in[4];
  const float* W0    = (const float*)d_in[5];
  const float* gamma = (const float*)d_in[6];
  const float* beta  = (const float*)d_in[7];
  float* out = (float*)d_out;
  float* ws  = (float*)d_ws;

  float* Pg  = ws;                        // 32768 floats
  float* Ut  = ws + 32768;                // 2097152 floats (U^T per chunk)
  float* Wpt = ws + 32768 + 2097152;      // 2097152 floats (Wprev^T per chunk)

  k_chunk<<<H * NC, 256, 0, stream>>>(
      (const float4*)q, (const float4*)k, k, v, gate, eta,
      (const float4*)W0, gamma, beta, Ut, Pg, out);
  k_scan<<<64, 256, 0, stream>>>(W0, (const float4*)Ut, Pg, (float4*)Wpt);
  k_out<<<H * NC, 256, 0, stream>>>(
      (const float4*)q, q, (const float4*)Wpt, Pg, gamma, beta, out);
}

// Round 7
// 32.466 us; speedup vs baseline: 4.0726x; 1.2155x over previous
//
#include <hip/hip_runtime.h>
#include <hip/hip_bf16.h>
#include <math.h>

// B=1, H=16, L=2048, D=64. Chunked gated recurrence, chunk C=64, NC=32.
// All 64^3 matmuls via v_mfma_f32_16x16x32_bf16 with FULL hi/lo split-bf16
// (3-MFMA emulation, rel err ~2^-17) on EVERY operand (LN row-normalization
// amplifies relative rounding by |mean|/|std|).
// LDS: 8 tiles x 8KB = 66KB -> 2 blocks/CU (grid 512 = fully resident).
// gt^T reuses the W0^T tiles (dead after M2); gt carried in regs across bar2.
// Tiles bf16 [64 rows][128B], XOR-swizzled (byte ^= (row&7)<<4).
// A row-major [M][K], B transposed [N][K]: every fragment is one ds_read_b128.
// C/D: row = 4*(l>>4)+reg, col = l&15 (m89-verified).

#define H 16
#define L 2048
#define D 64
#define C 64
#define NC 32

typedef short s8v __attribute__((ext_vector_type(8)));
typedef short s4v __attribute__((ext_vector_type(4)));
typedef float f4v __attribute__((ext_vector_type(4)));

__device__ inline unsigned short f2bf(float x) {
  unsigned u = __float_as_uint(x);
  return (unsigned short)((u + 0x7fffu + ((u >> 16) & 1u)) >> 16);
}
__device__ inline float bf2f(unsigned short s) { return __uint_as_float(((unsigned)s) << 16); }

__device__ inline int swz(int row, int colByte) { return row * 128 + (colByte ^ ((row & 7) << 4)); }

__device__ inline s8v ld8(const short* base, int row, int colByte) {
  return *(const s8v*)((const char*)base + swz(row, colByte));
}
__device__ inline void st4(short* base, int row, int colByte, s4v v) {
  *(s4v*)((char*)base + swz(row, colByte)) = v;
}
__device__ inline void st1(short* base, int row, int colByte, unsigned short v) {
  *(short*)((char*)base + swz(row, colByte)) = (short)v;
}

__device__ inline void red16(float& x) {
  x += __shfl_xor(x, 1, 64);
  x += __shfl_xor(x, 2, 64);
  x += __shfl_xor(x, 4, 64);
  x += __shfl_xor(x, 8, 64);
}

__device__ inline f4v MM(s8v a, s8v b, f4v c) {
  return __builtin_amdgcn_mfma_f32_16x16x32_bf16(a, b, c, 0, 0, 0);
}

// 3-MFMA split product: (Ah+Al)(Bh+Bl) ~= Ah*Bh + Ah*Bl + Al*Bh
__device__ inline f4v MM3(s8v ah, s8v al, s8v bh, s8v bl, f4v c) {
  c = MM(ah, bh, c);
  c = MM(ah, bl, c);
  c = MM(al, bh, c);
  return c;
}

// ---------------- Kernel 1: per-chunk gradl + QK^T + decay + Intra + U^T.
__global__ __launch_bounds__(256) void k_chunk(
    const float4* __restrict__ Q4, const float4* __restrict__ K4,
    const float* __restrict__ Kg, const float* __restrict__ Vg,
    const float* __restrict__ gate, const float* __restrict__ eta,
    const float4* __restrict__ W04, const float* __restrict__ gamma,
    const float* __restrict__ beta,
    float* __restrict__ Ut, float* __restrict__ Pg, float* __restrict__ Out)
{
  __shared__ __align__(16) short Qhi[4096];  // q rows hi (A M1); after bar2: S hi
  __shared__ __align__(16) short Qlo[4096];  // q rows lo;        after bar2: S lo
  __shared__ __align__(16) short Khi[4096];  // k rows hi (A M2; B M1)
  __shared__ __align__(16) short Klo[4096];  // k rows lo
  __shared__ __align__(16) short KtH[4096];  // (wj*k)^T [d][j] hi (B M4)
  __shared__ __align__(16) short KtL[4096];  // (wj*k)^T [d][j] lo
  __shared__ __align__(16) short W0h[4096];  // W0^T [e][d] hi (B M2); after bar2: gt^T hi
  __shared__ __align__(16) short W0l[4096];  // W0^T [e][d] lo;        after bar2: gt^T lo
  __shared__ float cl[64], wj[64];

  int tid = threadIdx.x;
  int h = blockIdx.x >> 5, c = blockIdx.x & 31;
  int rowb = h * L + c * C;

  // ---- gate log-cumsum first (staging needs wj)
  if (tid < 64) {
    float x = logf(fmaxf(gate[rowb + tid], 1e-37f));
    #pragma unroll
    for (int off = 1; off < 64; off <<= 1) {
      float n = __shfl_up(x, off, 64);
      if (tid >= off) x += n;
    }
    cl[tid] = x;
    float c63 = __shfl(x, 63, 64);
    wj[tid] = expf(c63 - x);
    Pg[rowb + tid] = expf(x);
  }
  __syncthreads();

  // ---- stage: fp32 -> bf16 hi/lo for q, k, wj*k^T, W0^T
  for (int idx = tid; idx < 1024; idx += 256) {
    int row = idx >> 4, g4 = idx & 15, cb = g4 * 8;
    float4 kv = K4[(rowb + row) * 16 + g4];
    float ke[4] = {kv.x, kv.y, kv.z, kv.w};
    float wr = wj[row];
    s4v khv, klv;
    #pragma unroll
    for (int e = 0; e < 4; ++e) {
      unsigned short hb = f2bf(ke[e]);
      khv[e] = (short)hb;
      klv[e] = (short)f2bf(ke[e] - bf2f(hb));
      float wk = ke[e] * wr;
      unsigned short wh = f2bf(wk);
      st1(KtH, 4 * g4 + e, 2 * row, wh);
      st1(KtL, 4 * g4 + e, 2 * row, f2bf(wk - bf2f(wh)));
    }
    st4(Khi, row, cb, khv);
    st4(Klo, row, cb, klv);
    float4 qv = Q4[(rowb + row) * 16 + g4];
    float qe[4] = {qv.x, qv.y, qv.z, qv.w};
    s4v qh, ql;
    #pragma unroll
    for (int e = 0; e < 4; ++e) {
      unsigned short hb = f2bf(qe[e]);
      qh[e] = (short)hb;
      ql[e] = (short)f2bf(qe[e] - bf2f(hb));
    }
    st4(Qhi, row, cb, qh);
    st4(Qlo, row, cb, ql);
    float4 wv = W04[h * 1024 + idx];
    float we[4] = {wv.x, wv.y, wv.z, wv.w};
    #pragma unroll
    for (int e = 0; e < 4; ++e) {
      unsigned short hb = f2bf(we[e]);
      st1(W0h, 4 * g4 + e, 2 * row, hb);
      st1(W0l, 4 * g4 + e, 2 * row, f2bf(we[e] - bf2f(hb)));
    }
  }
  __syncthreads();

  int R = tid >> 6, l = tid & 63, g = l >> 4, c16 = l & 15;
  int arow = 16 * R + c16;
  int kb0 = 16 * g, kb1 = 64 + 16 * g;

  // ---- M1: S[i][j] = q_i . k_j  (split x split)
  s8v aQh0 = ld8(Qhi, arow, kb0), aQh1 = ld8(Qhi, arow, kb1);
  s8v aQl0 = ld8(Qlo, arow, kb0), aQl1 = ld8(Qlo, arow, kb1);
  f4v accS[4];
  #pragma unroll
  for (int ct = 0; ct < 4; ++ct) {
    int br = 16 * ct + c16;
    f4v a = {0.f, 0.f, 0.f, 0.f};
    a = MM3(aQh0, aQl0, ld8(Khi, br, kb0), ld8(Klo, br, kb0), a);
    a = MM3(aQh1, aQl1, ld8(Khi, br, kb1), ld8(Klo, br, kb1), a);
    accS[ct] = a;
  }

  // ---- M2: Z1 = K @ W0  (split x split)
  s8v aKh0 = ld8(Khi, arow, kb0), aKh1 = ld8(Khi, arow, kb1);
  s8v aKl0 = ld8(Klo, arow, kb0), aKl1 = ld8(Klo, arow, kb1);
  f4v accZ[4];
  #pragma unroll
  for (int ct = 0; ct < 4; ++ct) {
    int br = 16 * ct + c16;
    f4v a = {0.f, 0.f, 0.f, 0.f};
    a = MM3(aKh0, aKl0, ld8(W0h, br, kb0), ld8(W0l, br, kb0), a);
    a = MM3(aKh1, aKl1, ld8(W0h, br, kb1), ld8(W0l, br, kb1), a);
    accZ[ct] = a;
  }

  // ---- LN-L2 backward (rows jr = 16R+4g+r, cols e = 16ct+c16), fp32 k,v.
  // gt kept in registers until bar2 (its LDS home is the W0 tiles, still live).
  float ga[4], be[4];
  #pragma unroll
  for (int ct = 0; ct < 4; ++ct) {
    ga[ct] = gamma[h * 64 + 16 * ct + c16];
    be[ct] = beta[h * 64 + 16 * ct + c16];
  }
  float gtreg[4][4];
  #pragma unroll
  for (int r = 0; r < 4; ++r) {
    int jr = 16 * R + 4 * g + r;
    int grow = (rowb + jr) * 64;
    float kk[4], vv[4];
    #pragma unroll
    for (int ct = 0; ct < 4; ++ct) {
      kk[ct] = Kg[grow + 16 * ct + c16];
      vv[ct] = Vg[grow + 16 * ct + c16];
    }
    float s1 = accZ[0][r] + accZ[1][r] + accZ[2][r] + accZ[3][r];
    red16(s1);
    float mu = s1 * (1.f / 64.f);
    float dv[4], s2 = 0.f;
    #pragma unroll
    for (int ct = 0; ct < 4; ++ct) { dv[ct] = accZ[ct][r] - mu; s2 += dv[ct] * dv[ct]; }
    red16(s2);
    float rstd = rsqrtf(s2 * (1.f / 64.f) + 1e-6f);
    float xh[4], gxh[4], t1 = 0.f, t2 = 0.f;
    #pragma unroll
    for (int ct = 0; ct < 4; ++ct) {
      xh[ct] = dv[ct] * rstd;
      float go = 2.f * (fmaf(ga[ct], xh[ct], be[ct]) + kk[ct] - vv[ct]);
      gxh[ct] = go * ga[ct];
      t1 += gxh[ct];
      t2 += gxh[ct] * xh[ct];
    }
    red16(t1);
    red16(t2);
    float m1 = t1 * (1.f / 64.f), m2 = t2 * (1.f / 64.f);
    float er = eta[rowb + jr];
    #pragma unroll
    for (int ct = 0; ct < 4; ++ct)
      gtreg[r][ct] = -er * (gxh[ct] - m1 - xh[ct] * m2) * rstd;
  }
  __syncthreads();   // bar2: all M1/M2 LDS reads done; Q and W0 tiles now dead

  // ---- write gt^T split into W0 tiles; decay+mask S split into Q tiles
  #pragma unroll
  for (int r = 0; r < 4; ++r) {
    int jr = 16 * R + 4 * g + r;
    #pragma unroll
    for (int ct = 0; ct < 4; ++ct) {
      float gtv = gtreg[r][ct];
      unsigned short hb = f2bf(gtv);
      st1(W0h, 16 * ct + c16, 2 * jr, hb);
      st1(W0l, 16 * ct + c16, 2 * jr, f2bf(gtv - bf2f(hb)));
    }
  }
  float cli[4];
  #pragma unroll
  for (int r = 0; r < 4; ++r) cli[r] = cl[16 * R + 4 * g + r];
  #pragma unroll
  for (int ct = 0; ct < 4; ++ct) {
    int j = 16 * ct + c16;
    float clj = cl[j];
    #pragma unroll
    for (int r = 0; r < 4; ++r) {
      int i = 16 * R + 4 * g + r;
      float s = (j <= i) ? accS[ct][r] * expf(cli[r] - clj) : 0.f;
      unsigned short hb = f2bf(s);
      st1(Qhi, i, 2 * j, hb);
      st1(Qlo, i, 2 * j, f2bf(s - bf2f(hb)));
    }
  }
  __syncthreads();   // bar3: gt^T visible to all waves

  // ---- M3: Intra[i][e] = sum_j S[i][j] gt[j][e]  (split x split)
  s8v aSh0 = ld8(Qhi, arow, kb0), aSh1 = ld8(Qhi, arow, kb1);
  s8v aSl0 = ld8(Qlo, arow, kb0), aSl1 = ld8(Qlo, arow, kb1);
  #pragma unroll
  for (int ct = 0; ct < 4; ++ct) {
    int br = 16 * ct + c16;
    f4v a = {0.f, 0.f, 0.f, 0.f};
    a = MM3(aSh0, aSl0, ld8(W0h, br, kb0), ld8(W0l, br, kb0), a);
    a = MM3(aSh1, aSl1, ld8(W0h, br, kb1), ld8(W0l, br, kb1), a);
    #pragma unroll
    for (int r = 0; r < 4; ++r)
      Out[(rowb + 16 * R + 4 * g + r) * 64 + 16 * ct + c16] = a[r];
  }

  // ---- M4: U^T[e][d] = sum_j gt[j][e] * (wj[j] k[j][d])  (split x split)
  float* ub = Ut + (h * NC + c) * 4096;
  s8v aGh0 = ld8(W0h, arow, kb0), aGh1 = ld8(W0h, arow, kb1);
  s8v aGl0 = ld8(W0l, arow, kb0), aGl1 = ld8(W0l, arow, kb1);
  #pragma unroll
  for (int ct = 0; ct < 4; ++ct) {
    int br = 16 * ct + c16;
    f4v a = {0.f, 0.f, 0.f, 0.f};
    a = MM3(aGh0, aGl0, ld8(KtH, br, kb0), ld8(KtL, br, kb0), a);
    a = MM3(aGh1, aGl1, ld8(KtH, br, kb1), ld8(KtL, br, kb1), a);
    #pragma unroll
    for (int r = 0; r < 4; ++r)
      ub[(16 * R + 4 * g + r) * 64 + 16 * ct + c16] = a[r];
  }
}

// ---------------- Kernel 2: chunk-state scan, one thread per (head, element).
// State layout W^T: idx = erow*64 + d (coalesced over d for Ut/Wpt traffic).
__global__ __launch_bounds__(256) void k_scan(
    const float* __restrict__ W0, const float* __restrict__ Ut,
    const float* __restrict__ Pg, float* __restrict__ Wpt)
{
  int t = blockIdx.x * 256 + threadIdx.x;   // [0, 65536)
  int h = t >> 12;
  int idx = t & 4095;
  int erow = idx >> 6, d = idx & 63;
  float w = W0[h * 4096 + d * 64 + erow];   // W0^T (read once, L2-resident)
  #pragma unroll
  for (int c2 = 0; c2 < NC; ++c2) {
    int off = (h * NC + c2) * 4096 + idx;
    Wpt[off] = w;
    w = fmaf(Pg[h * L + c2 * 64 + 63], w, Ut[off]);
  }
}

// ---------------- Kernel 3: Zq = Pg*(q @ Wprev) + Intra ; LN fwd ; +q
__global__ __launch_bounds__(256) void k_out(
    const float4* __restrict__ Q4, const float* __restrict__ Qg,
    const float4* __restrict__ Wpt4, const float* __restrict__ Pg,
    const float* __restrict__ gamma, const float* __restrict__ beta,
    float* __restrict__ Out)
{
  __shared__ __align__(16) short Qhi[4096];
  __shared__ __align__(16) short Qlo[4096];
  __shared__ __align__(16) short Whi[4096];  // Wprev^T [e][d] hi
  __shared__ __align__(16) short Wlo[4096];  // Wprev^T [e][d] lo
  int tid = threadIdx.x;
  int h = blockIdx.x >> 5, c = blockIdx.x & 31;
  int rowb = h * L + c * C;
  for (int idx = tid; idx < 1024; idx += 256) {
    int row = idx >> 4, g4 = idx & 15, cb = g4 * 8;
    float4 qv = Q4[(rowb + row) * 16 + g4];
    float qe[4] = {qv.x, qv.y, qv.z, qv.w};
    s4v qh, ql;
    #pragma unroll
    for (int e = 0; e < 4; ++e) {
      unsigned short hb = f2bf(qe[e]);
      qh[e] = (short)hb;
      ql[e] = (short)f2bf(qe[e] - bf2f(hb));
    }
    st4(Qhi, row, cb, qh);
    st4(Qlo, row, cb, ql);
    float4 wv = Wpt4[(h * NC + c) * 1024 + idx];
    float we[4] = {wv.x, wv.y, wv.z, wv.w};
    s4v wh, wl;
    #pragma unroll
    for (int e = 0; e < 4; ++e) {
      unsigned short hb = f2bf(we[e]);
      wh[e] = (short)hb;
      wl[e] = (short)f2bf(we[e] - bf2f(hb));
    }
    st4(Whi, row, cb, wh);
    st4(Wlo, row, cb, wl);
  }
  __syncthreads();

  int R = tid >> 6, l = tid & 63, g = l >> 4, c16 = l & 15;
  int arow = 16 * R + c16;
  int kb0 = 16 * g, kb1 = 64 + 16 * g;
  s8v ah0 = ld8(Qhi, arow, kb0), ah1 = ld8(Qhi, arow, kb1);
  s8v al0 = ld8(Qlo, arow, kb0), al1 = ld8(Qlo, arow, kb1);
  f4v acc[4];
  #pragma unroll
  for (int ct = 0; ct < 4; ++ct) {
    int br = 16 * ct + c16;
    f4v a = {0.f, 0.f, 0.f, 0.f};
    a = MM3(ah0, al0, ld8(Whi, br, kb0), ld8(Wlo, br, kb0), a);
    a = MM3(ah1, al1, ld8(Whi, br, kb1), ld8(Wlo, br, kb1), a);
    acc[ct] = a;
  }
  float ga[4], be[4];
  #pragma unroll
  for (int ct = 0; ct < 4; ++ct) {
    ga[ct] = gamma[h * 64 + 16 * ct + c16];
    be[ct] = beta[h * 64 + 16 * ct + c16];
  }
  #pragma unroll
  for (int r = 0; r < 4; ++r) {
    int row = rowb + 16 * R + 4 * g + r;
    float pr = Pg[row];
    float zq[4];
    #pragma unroll
    for (int ct = 0; ct < 4; ++ct)
      zq[ct] = fmaf(pr, acc[ct][r], Out[row * 64 + 16 * ct + c16]);
    float s1 = zq[0] + zq[1] + zq[2] + zq[3];
    red16(s1);
    float mu = s1 * (1.f / 64.f);
    float dv[4], s2 = 0.f;
    #pragma unroll
    for (int ct = 0; ct < 4; ++ct) { dv[ct] = zq[ct] - mu; s2 += dv[ct] * dv[ct]; }
    red16(s2);
    float rstd = rsqrtf(s2 * (1.f / 64.f) + 1e-6f);
    #pragma unroll
    for (int ct = 0; ct < 4; ++ct) {
      float o = fmaf(ga[ct], dv[ct] * rstd, be[ct]) + Qg[row * 64 + 16 * ct + c16];
      Out[row * 64 + 16 * ct + c16] = o;
    }
  }
}

extern "C" void kernel_launch(void* const* d_in, const int* in_sizes, int n_in,
                              void* d_out, int out_size, void* d_ws, size_t ws_size,
                              hipStream_t stream) {
  const float* q     = (const float*)d_in[0];
  const float* k     = (const float*)d_in[1];
  const float* v     = (const float*)d_in[2];
  const float* gate  = (const float*)d_in[3];
  const float* eta   = (const float*)d_in[4];
  const float* W0    = (const float*)d_in[5];
  const float* gamma = (const float*)d_in[6];
  const float* beta  = (const float*)d_in[7];
  float* out = (float*)d_out;
  float* ws  = (float*)d_ws;

  float* Pg  = ws;                        // 32768 floats
  float* Ut  = ws + 32768;                // 2097152 floats (U^T per chunk)
  float* Wpt = ws + 32768 + 2097152;      // 2097152 floats (Wprev^T per chunk)

  k_chunk<<<H * NC, 256, 0, stream>>>(
      (const float4*)q, (const float4*)k, k, v, gate, eta,
      (const float4*)W0, gamma, beta, Ut, Pg, out);
  k_scan<<<256, 256, 0, stream>>>(W0, Ut, Pg, Wpt);
  k_out<<<H * NC, 256, 0, stream>>>(
      (const float4*)q, q, (const float4*)Wpt, Pg, gamma, beta, out);
}

// Round 8
// 31.866 us; speedup vs baseline: 4.1493x; 1.0188x over previous
//
#include <hip/hip_runtime.h>
#include <hip/hip_bf16.h>
#include <math.h>

// B=1, H=16, L=2048, D=64. Chunked gated recurrence, chunk C=64, NC=32.
// All 64^3 matmuls via v_mfma_f32_16x16x32_bf16 with FULL hi/lo split-bf16
// (3-MFMA emulation, rel err ~2^-17) on EVERY operand (LN row-normalization
// amplifies relative rounding by |mean|/|std|).
// This rev: q A-fragments are lane-private -> loaded DIRECT from global into
// registers (no q LDS tiles); fp32 k/v/eta prefetched to regs at kernel top;
// transposed staging writes packed b32 (row pairs); gt^T writes st4-packed.
// LDS: 6 tiles x 8KB = 49.5KB. Grid 512 = 2 blocks/CU, fully resident.
// Tiles bf16 [64 rows][128B], XOR-swizzled (byte ^= (row&7)<<4).
// A row-major [M][K], B transposed [N][K]: every fragment is one ds_read_b128.
// C/D: row = 4*(l>>4)+reg, col = l&15 (m89-verified).

#define H 16
#define L 2048
#define D 64
#define C 64
#define NC 32

typedef short s8v __attribute__((ext_vector_type(8)));
typedef short s4v __attribute__((ext_vector_type(4)));
typedef float f4v __attribute__((ext_vector_type(4)));

__device__ inline unsigned short f2bf(float x) {
  unsigned u = __float_as_uint(x);
  return (unsigned short)((u + 0x7fffu + ((u >> 16) & 1u)) >> 16);
}
__device__ inline float bf2f(unsigned short s) { return __uint_as_float(((unsigned)s) << 16); }

__device__ inline int swz(int row, int colByte) { return row * 128 + (colByte ^ ((row & 7) << 4)); }

__device__ inline s8v ld8(const short* base, int row, int colByte) {
  return *(const s8v*)((const char*)base + swz(row, colByte));
}
__device__ inline void st4(short* base, int row, int colByte, s4v v) {
  *(s4v*)((char*)base + swz(row, colByte)) = v;
}
__device__ inline void st2(short* base, int row, int colByte, unsigned v) {
  *(unsigned*)((char*)base + swz(row, colByte)) = v;
}
__device__ inline void st1(short* base, int row, int colByte, unsigned short v) {
  *(short*)((char*)base + swz(row, colByte)) = (short)v;
}

__device__ inline void red16(float& x) {
  x += __shfl_xor(x, 1, 64);
  x += __shfl_xor(x, 2, 64);
  x += __shfl_xor(x, 4, 64);
  x += __shfl_xor(x, 8, 64);
}

__device__ inline f4v MM(s8v a, s8v b, f4v c) {
  return __builtin_amdgcn_mfma_f32_16x16x32_bf16(a, b, c, 0, 0, 0);
}

// 3-MFMA split product: (Ah+Al)(Bh+Bl) ~= Ah*Bh + Ah*Bl + Al*Bh
__device__ inline f4v MM3(s8v ah, s8v al, s8v bh, s8v bl, f4v c) {
  c = MM(ah, bh, c);
  c = MM(ah, bl, c);
  c = MM(al, bh, c);
  return c;
}

// ---------------- Kernel 1: per-chunk gradl + QK^T + decay + Intra + U^T.
__global__ __launch_bounds__(256, 2) void k_chunk(
    const float4* __restrict__ Q4, const float4* __restrict__ K4,
    const float* __restrict__ Kg, const float* __restrict__ Vg,
    const float* __restrict__ gate, const float* __restrict__ eta,
    const float4* __restrict__ W04, const float* __restrict__ gamma,
    const float* __restrict__ beta,
    float* __restrict__ Ut, float* __restrict__ Pg, float* __restrict__ Out)
{
  __shared__ __align__(16) short Khi[4096];  // k rows hi (A M2; B M1); after bar2: S hi
  __shared__ __align__(16) short Klo[4096];  // k rows lo;              after bar2: S lo
  __shared__ __align__(16) short KtH[4096];  // (wj*k)^T [d][j] hi (B M4)
  __shared__ __align__(16) short KtL[4096];  // (wj*k)^T [d][j] lo
  __shared__ __align__(16) short W0h[4096];  // W0^T [e][d] hi (B M2); after bar2: gt^T hi
  __shared__ __align__(16) short W0l[4096];  // W0^T [e][d] lo;        after bar2: gt^T lo
  __shared__ float cl[64], wj[64];

  int tid = threadIdx.x;
  int h = blockIdx.x >> 5, c = blockIdx.x & 31;
  int rowb = h * L + c * C;
  int R = tid >> 6, l = tid & 63, g = l >> 4, c16 = l & 15;
  int arow = 16 * R + c16;
  int kb0 = 16 * g, kb1 = 64 + 16 * g;

  // ---- early global loads (consumed late; hide HBM/L2 latency under staging+MFMA)
  const float4* qp = Q4 + (size_t)(rowb + arow) * 16;
  float4 qA0 = qp[2 * g], qA1 = qp[2 * g + 1], qA2 = qp[8 + 2 * g], qA3 = qp[8 + 2 * g + 1];
  float kk[4][4], vv[4][4], er[4];
  #pragma unroll
  for (int r = 0; r < 4; ++r) {
    int jr = 16 * R + 4 * g + r;
    const float* kp = Kg + (size_t)(rowb + jr) * 64 + c16;
    const float* vp = Vg + (size_t)(rowb + jr) * 64 + c16;
    #pragma unroll
    for (int ct = 0; ct < 4; ++ct) {
      kk[r][ct] = kp[16 * ct];
      vv[r][ct] = vp[16 * ct];
    }
    er[r] = eta[rowb + jr];
  }

  // ---- gate log-cumsum, computed redundantly per wave (no barrier needed:
  // each wave reads only its own writes of cl/wj; cross-wave writes identical)
  {
    float x = logf(fmaxf(gate[rowb + l], 1e-37f));
    #pragma unroll
    for (int off = 1; off < 64; off <<= 1) {
      float n = __shfl_up(x, off, 64);
      if (l >= off) x += n;
    }
    cl[l] = x;
    float c63 = __shfl(x, 63, 64);
    wj[l] = expf(c63 - x);
    if (R == 0) Pg[rowb + l] = expf(x);
  }

  // ---- stage k (rows hi/lo), (wj*k)^T and W0^T (b32-packed row pairs)
  #pragma unroll
  for (int it = 0; it < 2; ++it) {
    int idx = tid + it * 256;
    int rp = idx >> 4, g4 = idx & 15;
    int j0 = 2 * rp, j1 = j0 + 1;
    float4 k0 = K4[(size_t)(rowb + j0) * 16 + g4];
    float4 k1 = K4[(size_t)(rowb + j1) * 16 + g4];
    float4 w0 = W04[(size_t)h * 1024 + j0 * 16 + g4];
    float4 w1 = W04[(size_t)h * 1024 + j1 * 16 + g4];
    float w0j = wj[j0], w1j = wj[j1];
    float ke0[4] = {k0.x, k0.y, k0.z, k0.w};
    float ke1[4] = {k1.x, k1.y, k1.z, k1.w};
    float we0[4] = {w0.x, w0.y, w0.z, w0.w};
    float we1[4] = {w1.x, w1.y, w1.z, w1.w};
    s4v kh0, kl0, kh1, kl1;
    #pragma unroll
    for (int e = 0; e < 4; ++e) {
      unsigned short hb0 = f2bf(ke0[e]);
      kh0[e] = (short)hb0; kl0[e] = (short)f2bf(ke0[e] - bf2f(hb0));
      unsigned short hb1 = f2bf(ke1[e]);
      kh1[e] = (short)hb1; kl1[e] = (short)f2bf(ke1[e] - bf2f(hb1));
      int dr = 4 * g4 + e;
      float wk0 = ke0[e] * w0j, wk1 = ke1[e] * w1j;
      unsigned short th0 = f2bf(wk0), th1 = f2bf(wk1);
      st2(KtH, dr, 2 * j0, (unsigned)th0 | ((unsigned)th1 << 16));
      st2(KtL, dr, 2 * j0,
          (unsigned)f2bf(wk0 - bf2f(th0)) | ((unsigned)f2bf(wk1 - bf2f(th1)) << 16));
      unsigned short wh0 = f2bf(we0[e]), wh1 = f2bf(we1[e]);
      st2(W0h, dr, 2 * j0, (unsigned)wh0 | ((unsigned)wh1 << 16));
      st2(W0l, dr, 2 * j0,
          (unsigned)f2bf(we0[e] - bf2f(wh0)) | ((unsigned)f2bf(we1[e] - bf2f(wh1)) << 16));
    }
    st4(Khi, j0, 8 * g4, kh0); st4(Klo, j0, 8 * g4, kl0);
    st4(Khi, j1, 8 * g4, kh1); st4(Klo, j1, 8 * g4, kl1);
  }

  // ---- split q A-fragments in registers (no LDS)
  s8v aQh0, aQl0, aQh1, aQl1;
  {
    float q0[8] = {qA0.x, qA0.y, qA0.z, qA0.w, qA1.x, qA1.y, qA1.z, qA1.w};
    float q1[8] = {qA2.x, qA2.y, qA2.z, qA2.w, qA3.x, qA3.y, qA3.z, qA3.w};
    #pragma unroll
    for (int e = 0; e < 8; ++e) {
      unsigned short hb = f2bf(q0[e]);
      aQh0[e] = (short)hb; aQl0[e] = (short)f2bf(q0[e] - bf2f(hb));
      unsigned short hb1 = f2bf(q1[e]);
      aQh1[e] = (short)hb1; aQl1[e] = (short)f2bf(q1[e] - bf2f(hb1));
    }
  }
  __syncthreads();   // bar1: K/Kt/W0 tiles staged

  // ---- M1: S[i][j] = q_i . k_j  (split x split)
  f4v accS[4];
  #pragma unroll
  for (int ct = 0; ct < 4; ++ct) {
    int br = 16 * ct + c16;
    f4v a = {0.f, 0.f, 0.f, 0.f};
    a = MM3(aQh0, aQl0, ld8(Khi, br, kb0), ld8(Klo, br, kb0), a);
    a = MM3(aQh1, aQl1, ld8(Khi, br, kb1), ld8(Klo, br, kb1), a);
    accS[ct] = a;
  }

  // ---- M2: Z1 = K @ W0  (split x split)
  s8v aKh0 = ld8(Khi, arow, kb0), aKh1 = ld8(Khi, arow, kb1);
  s8v aKl0 = ld8(Klo, arow, kb0), aKl1 = ld8(Klo, arow, kb1);
  f4v accZ[4];
  #pragma unroll
  for (int ct = 0; ct < 4; ++ct) {
    int br = 16 * ct + c16;
    f4v a = {0.f, 0.f, 0.f, 0.f};
    a = MM3(aKh0, aKl0, ld8(W0h, br, kb0), ld8(W0l, br, kb0), a);
    a = MM3(aKh1, aKl1, ld8(W0h, br, kb1), ld8(W0l, br, kb1), a);
    accZ[ct] = a;
  }

  // ---- LN-L2 backward (rows jr = 16R+4g+r, cols e = 16ct+c16); k,v,eta in regs
  float ga[4], be[4];
  #pragma unroll
  for (int ct = 0; ct < 4; ++ct) {
    ga[ct] = gamma[h * 64 + 16 * ct + c16];
    be[ct] = beta[h * 64 + 16 * ct + c16];
  }
  float gtreg[4][4];
  #pragma unroll
  for (int r = 0; r < 4; ++r) {
    float s1 = accZ[0][r] + accZ[1][r] + accZ[2][r] + accZ[3][r];
    red16(s1);
    float mu = s1 * (1.f / 64.f);
    float dv[4], s2 = 0.f;
    #pragma unroll
    for (int ct = 0; ct < 4; ++ct) { dv[ct] = accZ[ct][r] - mu; s2 += dv[ct] * dv[ct]; }
    red16(s2);
    float rstd = rsqrtf(s2 * (1.f / 64.f) + 1e-6f);
    float xh[4], gxh[4], t1 = 0.f, t2 = 0.f;
    #pragma unroll
    for (int ct = 0; ct < 4; ++ct) {
      xh[ct] = dv[ct] * rstd;
      float go = 2.f * (fmaf(ga[ct], xh[ct], be[ct]) + kk[r][ct] - vv[r][ct]);
      gxh[ct] = go * ga[ct];
      t1 += gxh[ct];
      t2 += gxh[ct] * xh[ct];
    }
    red16(t1);
    red16(t2);
    float m1 = t1 * (1.f / 64.f), m2 = t2 * (1.f / 64.f);
    #pragma unroll
    for (int ct = 0; ct < 4; ++ct)
      gtreg[r][ct] = -er[r] * (gxh[ct] - m1 - xh[ct] * m2) * rstd;
  }
  __syncthreads();   // bar2: all M1/M2 LDS reads done; K and W0 tiles now dead

  // ---- gt^T split into W0 tiles (st4-packed along j); S split into K tiles
  #pragma unroll
  for (int ct = 0; ct < 4; ++ct) {
    s4v gh, gl;
    #pragma unroll
    for (int r = 0; r < 4; ++r) {
      unsigned short hb = f2bf(gtreg[r][ct]);
      gh[r] = (short)hb;
      gl[r] = (short)f2bf(gtreg[r][ct] - bf2f(hb));
    }
    st4(W0h, 16 * ct + c16, 2 * (16 * R + 4 * g), gh);
    st4(W0l, 16 * ct + c16, 2 * (16 * R + 4 * g), gl);
  }
  float cli[4];
  #pragma unroll
  for (int r = 0; r < 4; ++r) cli[r] = cl[16 * R + 4 * g + r];
  #pragma unroll
  for (int ct = 0; ct < 4; ++ct) {
    int j = 16 * ct + c16;
    float clj = cl[j];
    #pragma unroll
    for (int r = 0; r < 4; ++r) {
      int i = 16 * R + 4 * g + r;
      float s = (j <= i) ? accS[ct][r] * expf(cli[r] - clj) : 0.f;
      unsigned short hb = f2bf(s);
      st1(Khi, i, 2 * j, hb);
      st1(Klo, i, 2 * j, f2bf(s - bf2f(hb)));
    }
  }
  __syncthreads();   // bar3: S and gt^T visible to all waves

  // ---- M3: Intra[i][e] = sum_j S[i][j] gt[j][e]  (split x split)
  s8v aSh0 = ld8(Khi, arow, kb0), aSh1 = ld8(Khi, arow, kb1);
  s8v aSl0 = ld8(Klo, arow, kb0), aSl1 = ld8(Klo, arow, kb1);
  #pragma unroll
  for (int ct = 0; ct < 4; ++ct) {
    int br = 16 * ct + c16;
    f4v a = {0.f, 0.f, 0.f, 0.f};
    a = MM3(aSh0, aSl0, ld8(W0h, br, kb0), ld8(W0l, br, kb0), a);
    a = MM3(aSh1, aSl1, ld8(W0h, br, kb1), ld8(W0l, br, kb1), a);
    #pragma unroll
    for (int r = 0; r < 4; ++r)
      Out[(size_t)(rowb + 16 * R + 4 * g + r) * 64 + 16 * ct + c16] = a[r];
  }

  // ---- M4: U^T[e][d] = sum_j gt[j][e] * (wj[j] k[j][d])  (split x split)
  float* ub = Ut + (size_t)(h * NC + c) * 4096;
  s8v aGh0 = ld8(W0h, arow, kb0), aGh1 = ld8(W0h, arow, kb1);
  s8v aGl0 = ld8(W0l, arow, kb0), aGl1 = ld8(W0l, arow, kb1);
  #pragma unroll
  for (int ct = 0; ct < 4; ++ct) {
    int br = 16 * ct + c16;
    f4v a = {0.f, 0.f, 0.f, 0.f};
    a = MM3(aGh0, aGl0, ld8(KtH, br, kb0), ld8(KtL, br, kb0), a);
    a = MM3(aGh1, aGl1, ld8(KtH, br, kb1), ld8(KtL, br, kb1), a);
    #pragma unroll
    for (int r = 0; r < 4; ++r)
      ub[(16 * R + 4 * g + r) * 64 + 16 * ct + c16] = a[r];
  }
}

// ---------------- Kernel 2: chunk-state scan, one thread per (head, element).
__global__ __launch_bounds__(256) void k_scan(
    const float* __restrict__ W0, const float* __restrict__ Ut,
    const float* __restrict__ Pg, float* __restrict__ Wpt)
{
  int t = blockIdx.x * 256 + threadIdx.x;   // [0, 65536)
  int h = t >> 12;
  int idx = t & 4095;
  int erow = idx >> 6, d = idx & 63;
  float w = W0[h * 4096 + d * 64 + erow];   // W0^T (read once, L2-resident)
  #pragma unroll
  for (int c2 = 0; c2 < NC; ++c2) {
    int off = (h * NC + c2) * 4096 + idx;
    Wpt[off] = w;
    w = fmaf(Pg[h * L + c2 * 64 + 63], w, Ut[off]);
  }
}

// ---------------- Kernel 3: Zq = Pg*(q @ Wprev) + Intra ; LN fwd ; +q
__global__ __launch_bounds__(256, 2) void k_out(
    const float4* __restrict__ Q4, const float* __restrict__ Qg,
    const float4* __restrict__ Wpt4, const float* __restrict__ Pg,
    const float* __restrict__ gamma, const float* __restrict__ beta,
    float* __restrict__ Out)
{
  __shared__ __align__(16) short Whi[4096];  // Wprev^T [e][d] hi
  __shared__ __align__(16) short Wlo[4096];  // Wprev^T [e][d] lo
  int tid = threadIdx.x;
  int h = blockIdx.x >> 5, c = blockIdx.x & 31;
  int rowb = h * L + c * C;
  int R = tid >> 6, l = tid & 63, g = l >> 4, c16 = l & 15;
  int arow = 16 * R + c16;
  int kb0 = 16 * g, kb1 = 64 + 16 * g;

  // ---- early global loads
  const float4* qp = Q4 + (size_t)(rowb + arow) * 16;
  float4 qA0 = qp[2 * g], qA1 = qp[2 * g + 1], qA2 = qp[8 + 2 * g], qA3 = qp[8 + 2 * g + 1];
  float io[4][4], qres[4][4], pr[4];
  #pragma unroll
  for (int r = 0; r < 4; ++r) {
    int row = rowb + 16 * R + 4 * g + r;
    pr[r] = Pg[row];
    #pragma unroll
    for (int ct = 0; ct < 4; ++ct) {
      io[r][ct] = Out[(size_t)row * 64 + 16 * ct + c16];
      qres[r][ct] = Qg[(size_t)row * 64 + 16 * ct + c16];
    }
  }

  // ---- stage Wprev^T split
  for (int idx = tid; idx < 1024; idx += 256) {
    int row = idx >> 4, g4 = idx & 15;
    float4 wv = Wpt4[(size_t)(h * NC + c) * 1024 + idx];
    float we[4] = {wv.x, wv.y, wv.z, wv.w};
    s4v wh, wl;
    #pragma unroll
    for (int e = 0; e < 4; ++e) {
      unsigned short hb = f2bf(we[e]);
      wh[e] = (short)hb;
      wl[e] = (short)f2bf(we[e] - bf2f(hb));
    }
    st4(Whi, row, 8 * g4, wh);
    st4(Wlo, row, 8 * g4, wl);
  }

  // ---- split q A-fragments in registers
  s8v ah0, al0, ah1, al1;
  {
    float q0[8] = {qA0.x, qA0.y, qA0.z, qA0.w, qA1.x, qA1.y, qA1.z, qA1.w};
    float q1[8] = {qA2.x, qA2.y, qA2.z, qA2.w, qA3.x, qA3.y, qA3.z, qA3.w};
    #pragma unroll
    for (int e = 0; e < 8; ++e) {
      unsigned short hb = f2bf(q0[e]);
      ah0[e] = (short)hb; al0[e] = (short)f2bf(q0[e] - bf2f(hb));
      unsigned short hb1 = f2bf(q1[e]);
      ah1[e] = (short)hb1; al1[e] = (short)f2bf(q1[e] - bf2f(hb1));
    }
  }
  __syncthreads();

  f4v acc[4];
  #pragma unroll
  for (int ct = 0; ct < 4; ++ct) {
    int br = 16 * ct + c16;
    f4v a = {0.f, 0.f, 0.f, 0.f};
    a = MM3(ah0, al0, ld8(Whi, br, kb0), ld8(Wlo, br, kb0), a);
    a = MM3(ah1, al1, ld8(Whi, br, kb1), ld8(Wlo, br, kb1), a);
    acc[ct] = a;
  }
  float ga[4], be[4];
  #pragma unroll
  for (int ct = 0; ct < 4; ++ct) {
    ga[ct] = gamma[h * 64 + 16 * ct + c16];
    be[ct] = beta[h * 64 + 16 * ct + c16];
  }
  #pragma unroll
  for (int r = 0; r < 4; ++r) {
    int row = rowb + 16 * R + 4 * g + r;
    float zq[4];
    #pragma unroll
    for (int ct = 0; ct < 4; ++ct)
      zq[ct] = fmaf(pr[r], acc[ct][r], io[r][ct]);
    float s1 = zq[0] + zq[1] + zq[2] + zq[3];
    red16(s1);
    float mu = s1 * (1.f / 64.f);
    float dv[4], s2 = 0.f;
    #pragma unroll
    for (int ct = 0; ct < 4; ++ct) { dv[ct] = zq[ct] - mu; s2 += dv[ct] * dv[ct]; }
    red16(s2);
    float rstd = rsqrtf(s2 * (1.f / 64.f) + 1e-6f);
    #pragma unroll
    for (int ct = 0; ct < 4; ++ct) {
      float o = fmaf(ga[ct], dv[ct] * rstd, be[ct]) + qres[r][ct];
      Out[(size_t)row * 64 + 16 * ct + c16] = o;
    }
  }
}

extern "C" void kernel_launch(void* const* d_in, const int* in_sizes, int n_in,
                              void* d_out, int out_size, void* d_ws, size_t ws_size,
                              hipStream_t stream) {
  const float* q     = (const float*)d_in[0];
  const float* k     = (const float*)d_in[1];
  const float* v     = (const float*)d_in[2];
  const float* gate  = (const float*)d_in[3];
  const float* eta   = (const float*)d_in[4];
  const float* W0    = (const float*)d_in[5];
  const float* gamma = (const float*)d_in[6];
  const float* beta  = (const float*)d_in[7];
  float* out = (float*)d_out;
  float* ws  = (float*)d_ws;

  float* Pg  = ws;                        // 32768 floats
  float* Ut  = ws + 32768;                // 2097152 floats (U^T per chunk)
  float* Wpt = ws + 32768 + 2097152;      // 2097152 floats (Wprev^T per chunk)

  k_chunk<<<H * NC, 256, 0, stream>>>(
      (const float4*)q, (const float4*)k, k, v, gate, eta,
      (const float4*)W0, gamma, beta, Ut, Pg, out);
  k_scan<<<256, 256, 0, stream>>>(W0, Ut, Pg, Wpt);
  k_out<<<H * NC, 256, 0, stream>>>(
      (const float4*)q, q, (const float4*)Wpt, Pg, gamma, beta, out);
}